// Round 5
// baseline (3103.426 us; speedup 1.0000x reference)
//
#include <hip/hip_runtime.h>
#include <hip/hip_bf16.h>
#include <cstdint>
#include <cstddef>

#define D 512
#define NHEAD 8
#define LMAX 512
#define NGIN 3

typedef unsigned short u16;
typedef __attribute__((ext_vector_type(8))) short short8;
typedef __attribute__((ext_vector_type(8))) unsigned short ushort8;
typedef __attribute__((ext_vector_type(4))) float f32x4;

static __device__ inline u16 f2bf(float f){
    union { float f; uint32_t u; } c; c.f = f;
    uint32_t r = (c.u + 0x7fffu + ((c.u >> 16) & 1u)) >> 16;
    return (u16)r;
}

// ---------------- dtype probe + normalization ----------------
__global__ void probe_kernel(const int* __restrict__ ptr_raw,
                             const unsigned char* __restrict__ mask_raw,
                             int* __restrict__ flags){
    if (threadIdx.x == 0){
        flags[0] = (ptr_raw[1] == 0) ? 1 : 0;
        int cntOdd = 0, cnt4 = 0;
        for (int i = 1; i < 2048; i += 2) cntOdd += (mask_raw[i] != 0);
        for (int i = 4; i < 2048; i += 8) cnt4   += (mask_raw[i] != 0);
        flags[1] = (cntOdd > 64) ? 1 : ((cnt4 > 16) ? 4 : 8);
    }
}

__global__ void conv_int_kernel(const int* __restrict__ raw, int* __restrict__ outp,
                                const int* __restrict__ flags, int n){
    int i = blockIdx.x*256 + threadIdx.x;
    if (i < n) outp[i] = flags[0] ? raw[2*i] : raw[i];
}

__global__ void conv_mask_kernel(const unsigned char* __restrict__ raw,
                                 unsigned char* __restrict__ outp,
                                 const int* __restrict__ flags, int n){
    int w = flags[1];
    int i = blockIdx.x*256 + threadIdx.x;
    if (i < n) outp[i] = raw[(size_t)i * w];
}

// ---------------- CSR inversion ----------------
__global__ void count_kernel(const int* __restrict__ ei, int* __restrict__ deg, int E, int N){
    int e = blockIdx.x*256 + threadIdx.x;
    if (e < E){
        int d = ei[E + e];
        if ((unsigned)d < (unsigned)N) atomicAdd(&deg[d], 1);
    }
}

__global__ void scan_kernel(const int* __restrict__ deg, int* __restrict__ offs, int n){
    __shared__ int buf[1024];
    __shared__ int carry_s;
    int tid = threadIdx.x;
    if (tid == 0){ carry_s = 0; offs[0] = 0; }
    __syncthreads();
    int nChunks = (n + 1023) / 1024;
    for (int ch = 0; ch < nChunks; ch++){
        int i = ch*1024 + tid;
        int val = (i < n) ? deg[i] : 0;
        buf[tid] = val;
        __syncthreads();
        for (int off = 1; off < 1024; off <<= 1){
            int t = (tid >= off) ? buf[tid - off] : 0;
            __syncthreads();
            buf[tid] += t;
            __syncthreads();
        }
        if (i < n) offs[i+1] = carry_s + buf[tid];
        __syncthreads();
        if (tid == 0) carry_s += buf[1023];
        __syncthreads();
    }
}

__global__ void fill_kernel(const int* __restrict__ ei, const int* __restrict__ offs,
                            int* __restrict__ cursor, int* __restrict__ in_src, int E, int N){
    int e = blockIdx.x*256 + threadIdx.x;
    if (e < E){
        int d = ei[E + e];
        if ((unsigned)d < (unsigned)N){
            int slot = atomicAdd(&cursor[d], 1);
            in_src[offs[d] + slot] = ei[e];
        }
    }
}

// ---------------- gather ----------------
__global__ __launch_bounds__(256) void gather_kernel(const float* __restrict__ h,
        const int* __restrict__ offs, const int* __restrict__ in_src,
        float* __restrict__ out){
    int node = blockIdx.x;
    int tid = threadIdx.x;
    const float* hr = h + (size_t)node*D;
    float a0 = hr[tid], a1 = hr[tid+256];
    int s = offs[node], e = offs[node+1];
    for (int i = s; i < e; i++){
        const float* hs = h + (size_t)in_src[i]*D;
        a0 += hs[tid]; a1 += hs[tid+256];
    }
    float* orow = out + (size_t)node*D;
    orow[tid] = a0; orow[tid+256] = a1;
}

// ---------------- generic f32 GEMM (round-2-proven) ----------------
template<int ACT>
__global__ __launch_bounds__(256) void gemm_kernel(const float* __restrict__ A,
        const float* __restrict__ W, const float* __restrict__ bias,
        float* __restrict__ C, int K, int Nout){
    __shared__ float As[16][68];
    __shared__ float Ws[16][68];
    int tid = threadIdx.x;
    int rowBase = blockIdx.y * 64;
    int colBase = blockIdx.x * 64;
    int tx = tid & 15, ty = tid >> 4;
    int lrA = tid >> 2, lkA = (tid & 3) * 4;
    int lkW = tid >> 4, lcW = (tid & 15) * 4;
    float acc[4][4] = {};
    const float* Arow = A + (size_t)(rowBase + lrA)*K;
    for (int k0 = 0; k0 < K; k0 += 16){
        float4 a4 = *(const float4*)(Arow + k0 + lkA);
        As[lkA+0][lrA] = a4.x; As[lkA+1][lrA] = a4.y;
        As[lkA+2][lrA] = a4.z; As[lkA+3][lrA] = a4.w;
        float4 w4 = *(const float4*)(W + (size_t)(k0 + lkW)*Nout + colBase + lcW);
        *(float4*)&Ws[lkW][lcW] = w4;
        __syncthreads();
        #pragma unroll
        for (int k = 0; k < 16; k++){
            float4 av = *(const float4*)&As[k][ty*4];
            float4 wv = *(const float4*)&Ws[k][tx*4];
            float a_[4] = {av.x, av.y, av.z, av.w};
            float w_[4] = {wv.x, wv.y, wv.z, wv.w};
            #pragma unroll
            for (int i = 0; i < 4; i++)
                #pragma unroll
                for (int j = 0; j < 4; j++)
                    acc[i][j] += a_[i] * w_[j];
        }
        __syncthreads();
    }
    #pragma unroll
    for (int i = 0; i < 4; i++){
        int row = rowBase + ty*4 + i;
        float4 o;
        o.x = acc[i][0] + bias[colBase + tx*4 + 0];
        o.y = acc[i][1] + bias[colBase + tx*4 + 1];
        o.z = acc[i][2] + bias[colBase + tx*4 + 2];
        o.w = acc[i][3] + bias[colBase + tx*4 + 3];
        if (ACT){
            o.x = fmaxf(o.x, 0.f); o.y = fmaxf(o.y, 0.f);
            o.z = fmaxf(o.z, 0.f); o.w = fmaxf(o.w, 0.f);
        }
        *(float4*)(C + (size_t)row*Nout + colBase + tx*4) = o;
    }
}

// ---------------- weight transpose+convert: Wt[n][k] = bf16(W[k][n]) ----------------
__global__ __launch_bounds__(256) void transpose_kernel(const float* __restrict__ W,
        u16* __restrict__ Wt, int K, int Nout){
    __shared__ float T[32][33];
    int nb = blockIdx.x*32, kb = blockIdx.y*32;
    int ln = threadIdx.x & 31, lk = threadIdx.x >> 5;
    #pragma unroll
    for (int i = 0; i < 4; i++)
        T[lk + 8*i][ln] = W[(size_t)(kb + lk + 8*i)*Nout + nb + ln];
    __syncthreads();
    #pragma unroll
    for (int i = 0; i < 4; i++)
        Wt[(size_t)(nb + lk + 8*i)*K + kb + ln] = f2bf(T[ln][lk + 8*i]);
}

// ---------------- MFMA GEMM under test ----------------
#define GS 72
template<int ACT>
__global__ __launch_bounds__(256) void gemm_mfma(const float* __restrict__ A,
        const u16* __restrict__ Wt, const float* __restrict__ bias,
        float* __restrict__ C, int K, int Nout){
    __shared__ u16 As[128][GS];
    __shared__ u16 Bs[128][GS];
    int tid = threadIdx.x;
    int rowBase = blockIdx.y*128, colBase = blockIdx.x*128;
    int w = tid >> 6, l = tid & 63, lg = l >> 4, lm = l & 15;
    int wr = w >> 1, wc = w & 1;
    f32x4 acc[4][4] = {};
    int sr = tid >> 1, skb = (tid & 1)*32;
    const float* Ap = A  + (size_t)(rowBase + sr)*K + skb;
    const u16*  Wp = Wt + (size_t)(colBase + sr)*K + skb;
    for (int k0 = 0; k0 < K; k0 += 64){
        #pragma unroll
        for (int i = 0; i < 4; i++){
            float4 f0 = *(const float4*)(Ap + k0 + i*8);
            float4 f1 = *(const float4*)(Ap + k0 + i*8 + 4);
            ushort8 pk;
            pk[0]=f2bf(f0.x); pk[1]=f2bf(f0.y); pk[2]=f2bf(f0.z); pk[3]=f2bf(f0.w);
            pk[4]=f2bf(f1.x); pk[5]=f2bf(f1.y); pk[6]=f2bf(f1.z); pk[7]=f2bf(f1.w);
            *(ushort8*)&As[sr][skb + i*8] = pk;
        }
        #pragma unroll
        for (int i = 0; i < 4; i++)
            *(ushort8*)&Bs[sr][skb + i*8] = *(const ushort8*)(Wp + k0 + i*8);
        __syncthreads();
        #pragma unroll
        for (int ks = 0; ks < 2; ks++){
            short8 af[4], bfr[4];
            #pragma unroll
            for (int mf = 0; mf < 4; mf++)
                af[mf] = *(const short8*)&As[wr*64 + mf*16 + lm][ks*32 + lg*8];
            #pragma unroll
            for (int nf = 0; nf < 4; nf++)
                bfr[nf] = *(const short8*)&Bs[wc*64 + nf*16 + lm][ks*32 + lg*8];
            #pragma unroll
            for (int mf = 0; mf < 4; mf++)
                #pragma unroll
                for (int nf = 0; nf < 4; nf++)
                    acc[mf][nf] = __builtin_amdgcn_mfma_f32_16x16x32_bf16(af[mf], bfr[nf], acc[mf][nf], 0, 0, 0);
        }
        __syncthreads();
    }
    #pragma unroll
    for (int nf = 0; nf < 4; nf++){
        int col = colBase + wc*64 + nf*16 + lm;
        float bv = bias[col];
        #pragma unroll
        for (int mf = 0; mf < 4; mf++){
            int row = rowBase + wr*64 + mf*16 + lg*4;
            #pragma unroll
            for (int j = 0; j < 4; j++){
                float o = acc[mf][nf][j] + bv;
                if (ACT) o = fmaxf(o, 0.f);
                C[(size_t)(row + j)*Nout + col] = o;
            }
        }
    }
}

// ---------------- diag: max|a-b| reductions ----------------
__global__ void maxdiff_kernel(const float* __restrict__ a, const float* __restrict__ b,
                               unsigned* __restrict__ cell, int rows, int cols, int lda, int total){
    int i = blockIdx.x*256 + threadIdx.x;
    float d = 0.f;
    if (i < total){
        int r = i / cols, c = i - r*cols;
        size_t off = (size_t)r*lda + c;
        d = fabsf(a[off] - b[off]);
    }
    #pragma unroll
    for (int off = 32; off > 0; off >>= 1) d = fmaxf(d, __shfl_xor(d, off));
    if ((threadIdx.x & 63) == 0) atomicMax(cell, __float_as_uint(d));
}

// compare a[r][c] vs b[c][r] over the origin 16x16 subtile
__global__ void swapdiff_kernel(const float* __restrict__ a, const float* __restrict__ b,
                                unsigned* __restrict__ cell){
    int t = threadIdx.x;       // 256 threads
    int r = t >> 4, c = t & 15;
    float d = fabsf(a[(size_t)r*512 + c] - b[(size_t)c*512 + r]);
    atomicMax(cell, __float_as_uint(d));
}

__global__ void diag_write_kernel(const unsigned* __restrict__ u, float* __restrict__ out, int enabled){
    if (threadIdx.x != 0) return;
    if (!enabled){ out[0] = 9000.f; return; }
    float g1 = __uint_as_float(u[0]);   // tile(0,0) 128x128 diff
    float g2 = __uint_as_float(u[1]);   // global diff
    float g3 = __uint_as_float(u[2]);   // subtile-transpose diff
    bool b1 = g1 > 0.25f, b2 = g2 > 0.25f, b3 = g3 > 0.25f;
    float val = 0.f;
    if (b1 && b2)      val = b3 ? 8000.f : 4000.f;  // in-tile bug; 4000 = C/D swap confirmed
    else if (!b1 && b2) val = 7000.f;               // cross-tile bug
    else if (b1 && !b2) val = 2000.f;               // inconsistent
    if (val != 0.f) out[0] = val;
}

// ---------------- BatchNorm ----------------
__global__ __launch_bounds__(256) void bn_stats_kernel(const float* __restrict__ A,
        float* __restrict__ sums, int n){
    int c = threadIdx.x;
    int r0 = blockIdx.x*128, r1 = min(n, r0+128);
    float s0=0.f, s1=0.f, q0=0.f, q1=0.f;
    for (int r = r0; r < r1; r++){
        float v0 = A[(size_t)r*D + c];
        float v1 = A[(size_t)r*D + 256 + c];
        s0 += v0; q0 += v0*v0; s1 += v1; q1 += v1*v1;
    }
    atomicAdd(&sums[c], s0);
    atomicAdd(&sums[c+256], s1);
    atomicAdd(&sums[512+c], q0);
    atomicAdd(&sums[512+c+256], q1);
}

__global__ void bn_final_kernel(const float* __restrict__ sums, const float* __restrict__ gamma,
        const float* __restrict__ beta, float* __restrict__ sc, int n){
    int c = threadIdx.x;
    float mean = sums[c] / (float)n;
    float var = sums[512+c] / (float)n - mean*mean;
    float r = rsqrtf(var + 1e-5f);
    float scale = r * gamma[c];
    sc[c] = scale;
    sc[512+c] = beta[c] - mean*scale;
}

__global__ void bn_apply_kernel(const float* __restrict__ in, const float* __restrict__ sc,
        float* __restrict__ out, int total4){
    int i = blockIdx.x*256 + threadIdx.x;
    if (i >= total4) return;
    int c4 = (i*4) & (D-1);
    float4 vv = *(const float4*)(in + (size_t)i*4);
    float4 s  = *(const float4*)(sc + c4);
    float4 sh = *(const float4*)(sc + 512 + c4);
    float4 o;
    o.x = vv.x*s.x + sh.x; o.y = vv.y*s.y + sh.y;
    o.z = vv.z*s.z + sh.z; o.w = vv.w*s.w + sh.w;
    *(float4*)(out + (size_t)i*4) = o;
}

// ---------------- ragged masked flash attention (f32, round-2-proven) ----------------
__global__ __launch_bounds__(256) void attn_kernel(const float* __restrict__ qk,
        const float* __restrict__ v, const unsigned char* __restrict__ mask,
        const int* __restrict__ ptr, float* __restrict__ out, int N){
    __shared__ float Kt[64][65];
    __shared__ float Vs[64][68];
    __shared__ float Qs[16][68];
    __shared__ float Ps[4][64];
    int b = blockIdx.z, h = blockIdx.y;
    int base = ptr[b];
    int size = ptr[b+1] - base;
    if (base < 0) base = 0; if (base > N) base = N;
    if (size < 0) size = 0; if (size > N - base) size = N - base;
    int rowBase = blockIdx.x * 16;
    if (rowBase >= size) return;
    int tid = threadIdx.x;
    int w = tid >> 6, lane = tid & 63;
    {
        int rl = tid >> 4, c4 = (tid & 15) * 4;
        int r = rowBase + rl;
        float4 q4 = make_float4(0.f, 0.f, 0.f, 0.f);
        if (r < size)
            q4 = *(const float4*)(qk + (size_t)(base + r)*1024 + 512 + h*64 + c4);
        *(float4*)&Qs[rl][c4] = q4;
    }
    float m[4], l[4], acc[4];
    #pragma unroll
    for (int i = 0; i < 4; i++){ m[i] = -INFINITY; l[i] = 0.f; acc[i] = 0.f; }
    int nt = (size + 63) >> 6;
    for (int t = 0; t < nt; t++){
        int jBase = t * 64;
        __syncthreads();
        #pragma unroll
        for (int p = 0; p < 4; p++){
            int idx = tid + p*256;
            int rl = idx >> 4, c4 = (idx & 15) * 4;
            int j = jBase + rl;
            float4 kk = make_float4(0.f,0.f,0.f,0.f), vv = make_float4(0.f,0.f,0.f,0.f);
            if (j < size){
                size_t node = (size_t)(base + j);
                kk = *(const float4*)(qk + node*1024 + h*64 + c4);
                vv = *(const float4*)(v  + node*512  + h*64 + c4);
            }
            Kt[c4+0][rl] = kk.x; Kt[c4+1][rl] = kk.y;
            Kt[c4+2][rl] = kk.z; Kt[c4+3][rl] = kk.w;
            *(float4*)&Vs[rl][c4] = vv;
        }
        __syncthreads();
        for (int ri = 0; ri < 4; ri++){
            int r = rowBase + w*4 + ri;
            if (r >= size) continue;
            int j = jBase + lane;
            float s = -INFINITY;
            if (j < size && !mask[((size_t)b*LMAX + r)*LMAX + j]){
                float dot = 0.f;
                const float* qrow = Qs[w*4 + ri];
                #pragma unroll
                for (int d = 0; d < 64; d++) dot += qrow[d] * Kt[d][lane];
                s = dot * 0.125f;
            }
            float tm = s;
            #pragma unroll
            for (int off = 32; off > 0; off >>= 1) tm = fmaxf(tm, __shfl_xor(tm, off));
            if (tm == -INFINITY) continue;
            float mnew = fmaxf(m[ri], tm);
            float alpha = __expf(m[ri] - mnew);
            float p = (s == -INFINITY) ? 0.f : __expf(s - mnew);
            float psum = p;
            #pragma unroll
            for (int off = 32; off > 0; off >>= 1) psum += __shfl_xor(psum, off);
            m[ri] = mnew;
            l[ri] = l[ri]*alpha + psum;
            Ps[w][lane] = p;
            float a2 = 0.f;
            #pragma unroll
            for (int jj = 0; jj < 64; jj++) a2 += Ps[w][jj] * Vs[jj][lane];
            acc[ri] = acc[ri]*alpha + a2;
        }
    }
    #pragma unroll
    for (int ri = 0; ri < 4; ri++){
        int r = rowBase + w*4 + ri;
        if (r < size) out[(size_t)(base + r)*512 + h*64 + lane] = acc[ri] / l[ri];
    }
}

extern "C" void kernel_launch(void* const* d_in, const int* in_sizes, int n_in,
                              void* d_out, int out_size, void* d_ws, size_t ws_size,
                              hipStream_t stream){
    const float* x        = (const float*)d_in[0];
    const int*   ei_raw   = (const int*)d_in[1];
    const unsigned char* mask_raw = (const unsigned char*)d_in[2];
    const int*   ptr_raw  = (const int*)d_in[3];
    const float* gin_w1   = (const float*)d_in[4];
    const float* gin_b1   = (const float*)d_in[5];
    const float* gin_w2   = (const float*)d_in[6];
    const float* gin_b2   = (const float*)d_in[7];
    const float* bn_gamma = (const float*)d_in[8];
    const float* bn_beta  = (const float*)d_in[9];
    const float* se_w     = (const float*)d_in[10];
    const float* se_b     = (const float*)d_in[11];
    const float* qk_w     = (const float*)d_in[12];
    const float* qk_b     = (const float*)d_in[13];
    const float* v_w      = (const float*)d_in[14];
    const float* v_b      = (const float*)d_in[15];
    const float* out_w    = (const float*)d_in[16];
    const float* out_b    = (const float*)d_in[17];

    const int N  = in_sizes[0] / D;       // 12160
    const int E  = in_sizes[1] / 2;       // 97280
    const int B  = in_sizes[3] - 1;       // 32
    const int Mn = in_sizes[2];           // B*512*512

    char* ws = (char*)d_ws;
    size_t NB = (size_t)N * D * sizeof(float);
    float* vbuf  = (float*)(ws);
    float* bufA  = (float*)(ws + NB);
    float* bufB  = (float*)(ws + 2*NB);
    float* bufC  = (float*)(ws + 3*NB);
    float* qkbuf = bufA;
    char* p = ws + 4*NB;
    auto alloc = [&](size_t bytes) -> char* {
        char* q = p; p += (bytes + 255) & ~(size_t)255; return q;
    };
    float* sums   = (float*)alloc(1024*sizeof(float));
    float* sc     = (float*)alloc(1024*sizeof(float));
    int*   flags  = (int*)alloc(16*sizeof(int));
    int*   deg    = (int*)alloc((size_t)N*sizeof(int));
    int*   offs   = (int*)alloc((size_t)(N+1)*sizeof(int));
    int*   cursor = (int*)alloc((size_t)N*sizeof(int));
    int*   in_src = (int*)alloc((size_t)E*sizeof(int));
    int*   ptr32  = (int*)alloc(64*sizeof(int));
    int*   ei32   = (int*)alloc((size_t)2*E*sizeof(int));
    unsigned char* mask8 = (unsigned char*)alloc((size_t)Mn);
    // diag scratch
    u16*      wt_v  = (u16*)alloc((size_t)D*D*sizeof(u16));
    float*    mtest = (float*)alloc(NB);
    unsigned* udiff = (unsigned*)alloc(64);
    int do_diag = ((size_t)(p - ws) <= ws_size) ? 1 : 0;

    // --- dtype probe + normalization ---
    probe_kernel<<<1, 64, 0, stream>>>(ptr_raw, mask_raw, flags);
    conv_int_kernel<<<1, 64, 0, stream>>>(ptr_raw, ptr32, flags, B + 1);
    conv_int_kernel<<<(2*E + 255)/256, 256, 0, stream>>>(ei_raw, ei32, flags, 2*E);
    conv_mask_kernel<<<(Mn + 255)/256, 256, 0, stream>>>(mask_raw, mask8, flags, Mn);

    // --- CSR inversion ---
    hipMemsetAsync(deg, 0, (size_t)N*sizeof(int), stream);
    hipMemsetAsync(cursor, 0, (size_t)N*sizeof(int), stream);
    count_kernel<<<(E+255)/256, 256, 0, stream>>>(ei32, deg, E, N);
    scan_kernel<<<1, 1024, 0, stream>>>(deg, offs, N);
    fill_kernel<<<(E+255)/256, 256, 0, stream>>>(ei32, offs, cursor, in_src, E, N);

    dim3 g512(512/64, N/64), g1024(1024/64, N/64);

    // v = x @ v_w + v_b (f32 reference path)
    gemm_kernel<0><<<g512, 256, 0, stream>>>(x, v_w, v_b, vbuf, D, D);

    // --- MFMA self-test: same GEMM via gemm_mfma, compare to vbuf ---
    if (do_diag){
        hipMemsetAsync(udiff, 0, 64, stream);
        transpose_kernel<<<dim3(16,16), 256, 0, stream>>>(v_w, wt_v, D, D);
        gemm_mfma<0><<<dim3(4, N/128), 256, 0, stream>>>(x, wt_v, v_b, mtest, D, D);
        maxdiff_kernel<<<(128*128 + 255)/256, 256, 0, stream>>>(mtest, vbuf, &udiff[0], 128, 128, 512, 128*128);
        maxdiff_kernel<<<((N*512) + 255)/256, 256, 0, stream>>>(mtest, vbuf, &udiff[1], N, 512, 512, N*512);
        swapdiff_kernel<<<1, 256, 0, stream>>>(mtest, vbuf, &udiff[2]);
    }

    // GIN layers
    const float* h = x;
    for (int i = 0; i < NGIN; i++){
        gather_kernel<<<N, 256, 0, stream>>>(h, offs, in_src, bufB);
        gemm_kernel<1><<<g512, 256, 0, stream>>>(bufB, gin_w1 + (size_t)i*D*D, gin_b1 + (size_t)i*D, bufC, D, D);
        gemm_kernel<1><<<g512, 256, 0, stream>>>(bufC, gin_w2 + (size_t)i*D*D, gin_b2 + (size_t)i*D, bufA, D, D);
        h = bufA;
    }

    // BatchNorm
    hipMemsetAsync(sums, 0, 1024*sizeof(float), stream);
    bn_stats_kernel<<<(N+127)/128, 256, 0, stream>>>(bufA, sums, N);
    bn_final_kernel<<<1, 512, 0, stream>>>(sums, bn_gamma, bn_beta, sc, N);
    bn_apply_kernel<<<(N*D/4 + 255)/256, 256, 0, stream>>>(bufA, sc, bufB, N*D/4);

    // x_struct = bn(h) @ se_w + se_b
    gemm_kernel<0><<<g512, 256, 0, stream>>>(bufB, se_w, se_b, bufC, D, D);

    // qk = x_struct @ qk_w + qk_b
    gemm_kernel<0><<<g1024, 256, 0, stream>>>(bufC, qk_w, qk_b, qkbuf, D, 1024);

    // attention -> bufC
    attn_kernel<<<dim3(LMAX/16, NHEAD, B), 256, 0, stream>>>(qkbuf, vbuf, mask8, ptr32, bufC, N);

    // out = attn_out @ out_w + out_b
    gemm_kernel<0><<<g512, 256, 0, stream>>>(bufC, out_w, out_b, (float*)d_out, D, D);

    // diag verdict (overwrites d_out[0] only when MFMA mismatches)
    diag_write_kernel<<<1, 64, 0, stream>>>(udiff, (float*)d_out, do_diag);
}

// Round 6
// 1331.565 us; speedup vs baseline: 2.3307x; 2.3307x over previous
//
#include <hip/hip_runtime.h>
#include <hip/hip_bf16.h>
#include <cstdint>
#include <cstddef>

#define D 512
#define NHEAD 8
#define LMAX 512
#define NGIN 3

typedef unsigned short u16;
typedef __attribute__((ext_vector_type(8))) short short8;
typedef __attribute__((ext_vector_type(8))) unsigned short ushort8;
typedef __attribute__((ext_vector_type(4))) float f32x4;

static __device__ inline u16 f2bf(float f){
    union { float f; uint32_t u; } c; c.f = f;
    uint32_t r = (c.u + 0x7fffu + ((c.u >> 16) & 1u)) >> 16;
    return (u16)r;
}
static __device__ inline float bf2f(u16 h){
    union { uint32_t u; float f; } c; c.u = ((uint32_t)h) << 16; return c.f;
}

// ---------------- dtype probe + normalization ----------------
__global__ void probe_kernel(const int* __restrict__ ptr_raw,
                             const unsigned char* __restrict__ mask_raw,
                             int* __restrict__ flags){
    if (threadIdx.x == 0){
        flags[0] = (ptr_raw[1] == 0) ? 1 : 0;
        int cntOdd = 0, cnt4 = 0;
        for (int i = 1; i < 2048; i += 2) cntOdd += (mask_raw[i] != 0);
        for (int i = 4; i < 2048; i += 8) cnt4   += (mask_raw[i] != 0);
        flags[1] = (cntOdd > 64) ? 1 : ((cnt4 > 16) ? 4 : 8);
    }
}

__global__ void conv_int_kernel(const int* __restrict__ raw, int* __restrict__ outp,
                                const int* __restrict__ flags, int n){
    int i = blockIdx.x*256 + threadIdx.x;
    if (i < n) outp[i] = flags[0] ? raw[2*i] : raw[i];
}

__global__ void conv_mask_kernel(const unsigned char* __restrict__ raw,
                                 unsigned char* __restrict__ outp,
                                 const int* __restrict__ flags, int n){
    int w = flags[1];
    int i = blockIdx.x*256 + threadIdx.x;
    if (i < n) outp[i] = raw[(size_t)i * w];
}

// ---------------- CSR inversion ----------------
__global__ void count_kernel(const int* __restrict__ ei, int* __restrict__ deg, int E, int N){
    int e = blockIdx.x*256 + threadIdx.x;
    if (e < E){
        int d = ei[E + e];
        if ((unsigned)d < (unsigned)N) atomicAdd(&deg[d], 1);
    }
}

__global__ void scan_kernel(const int* __restrict__ deg, int* __restrict__ offs, int n){
    __shared__ int buf[1024];
    __shared__ int carry_s;
    int tid = threadIdx.x;
    if (tid == 0){ carry_s = 0; offs[0] = 0; }
    __syncthreads();
    int nChunks = (n + 1023) / 1024;
    for (int ch = 0; ch < nChunks; ch++){
        int i = ch*1024 + tid;
        int val = (i < n) ? deg[i] : 0;
        buf[tid] = val;
        __syncthreads();
        for (int off = 1; off < 1024; off <<= 1){
            int t = (tid >= off) ? buf[tid - off] : 0;
            __syncthreads();
            buf[tid] += t;
            __syncthreads();
        }
        if (i < n) offs[i+1] = carry_s + buf[tid];
        __syncthreads();
        if (tid == 0) carry_s += buf[1023];
        __syncthreads();
    }
}

__global__ void fill_kernel(const int* __restrict__ ei, const int* __restrict__ offs,
                            int* __restrict__ cursor, int* __restrict__ in_src, int E, int N){
    int e = blockIdx.x*256 + threadIdx.x;
    if (e < E){
        int d = ei[E + e];
        if ((unsigned)d < (unsigned)N){
            int slot = atomicAdd(&cursor[d], 1);
            in_src[offs[d] + slot] = ei[e];
        }
    }
}

// ---------------- gather ----------------
__global__ __launch_bounds__(256) void gather_kernel(const float* __restrict__ h,
        const int* __restrict__ offs, const int* __restrict__ in_src,
        float* __restrict__ out){
    int node = blockIdx.x;
    int tid = threadIdx.x;
    const float* hr = h + (size_t)node*D;
    float a0 = hr[tid], a1 = hr[tid+256];
    int s = offs[node], e = offs[node+1];
    for (int i = s; i < e; i++){
        const float* hs = h + (size_t)in_src[i]*D;
        a0 += hs[tid]; a1 += hs[tid+256];
    }
    float* orow = out + (size_t)node*D;
    orow[tid] = a0; orow[tid+256] = a1;
}

// ---------------- weight transpose + split-bf16 convert ----------------
// Wh[n][k] = bf16(W[k][n]); Wl[n][k] = bf16(W[k][n] - Wh[n][k])
__global__ __launch_bounds__(256) void transpose_kernel(const float* __restrict__ W,
        u16* __restrict__ Wh, u16* __restrict__ Wl, int K, int Nout){
    __shared__ float T[32][33];
    int nb = blockIdx.x*32, kb = blockIdx.y*32;
    int ln = threadIdx.x & 31, lk = threadIdx.x >> 5;
    #pragma unroll
    for (int i = 0; i < 4; i++)
        T[lk + 8*i][ln] = W[(size_t)(kb + lk + 8*i)*Nout + nb + ln];
    __syncthreads();
    #pragma unroll
    for (int i = 0; i < 4; i++){
        float val = T[ln][lk + 8*i];
        u16 h = f2bf(val);
        size_t idx = (size_t)(nb + lk + 8*i)*K + kb + ln;
        Wh[idx] = h;
        Wl[idx] = f2bf(val - bf2f(h));
    }
}

// ---------------- split-bf16 MFMA GEMM: C = act(A[M,K]f32 @ W + bias), f32 out ----------------
// 3-term: Ah*Bh + Al*Bh + Ah*Bl  (per-element error ~2^-17, f32-class).
// 128x128 tile, BK=64, 4 waves (2x2) x 64x64. Verified layout (round-5 self-test).
#define GS 72
template<int ACT>
__global__ __launch_bounds__(256) void gemm_mfma(const float* __restrict__ A,
        const u16* __restrict__ Wth, const u16* __restrict__ Wtl,
        const float* __restrict__ bias,
        float* __restrict__ C, int K, int Nout){
    __shared__ u16 Ah[128][GS];
    __shared__ u16 Al[128][GS];
    __shared__ u16 Bh[128][GS];
    __shared__ u16 Bl[128][GS];
    int tid = threadIdx.x;
    int rowBase = blockIdx.y*128, colBase = blockIdx.x*128;
    int w = tid >> 6, l = tid & 63, lg = l >> 4, lm = l & 15;
    int wr = w >> 1, wc = w & 1;
    f32x4 acc[4][4] = {};
    int sr = tid >> 1, skb = (tid & 1)*32;
    const float* Ap  = A   + (size_t)(rowBase + sr)*K + skb;
    const u16*  Wph = Wth + (size_t)(colBase + sr)*K + skb;
    const u16*  Wpl = Wtl + (size_t)(colBase + sr)*K + skb;
    for (int k0 = 0; k0 < K; k0 += 64){
        #pragma unroll
        for (int i = 0; i < 4; i++){
            float4 f0 = *(const float4*)(Ap + k0 + i*8);
            float4 f1 = *(const float4*)(Ap + k0 + i*8 + 4);
            float fv[8] = {f0.x,f0.y,f0.z,f0.w,f1.x,f1.y,f1.z,f1.w};
            ushort8 ph, pl;
            #pragma unroll
            for (int j = 0; j < 8; j++){
                u16 hh = f2bf(fv[j]);
                ph[j] = hh;
                pl[j] = f2bf(fv[j] - bf2f(hh));
            }
            *(ushort8*)&Ah[sr][skb + i*8] = ph;
            *(ushort8*)&Al[sr][skb + i*8] = pl;
        }
        #pragma unroll
        for (int i = 0; i < 4; i++){
            *(ushort8*)&Bh[sr][skb + i*8] = *(const ushort8*)(Wph + k0 + i*8);
            *(ushort8*)&Bl[sr][skb + i*8] = *(const ushort8*)(Wpl + k0 + i*8);
        }
        __syncthreads();
        #pragma unroll
        for (int ks = 0; ks < 2; ks++){
            short8 ah[4], al[4], bh[4], bl[4];
            #pragma unroll
            for (int mf = 0; mf < 4; mf++){
                ah[mf] = *(const short8*)&Ah[wr*64 + mf*16 + lm][ks*32 + lg*8];
                al[mf] = *(const short8*)&Al[wr*64 + mf*16 + lm][ks*32 + lg*8];
            }
            #pragma unroll
            for (int nf = 0; nf < 4; nf++){
                bh[nf] = *(const short8*)&Bh[wc*64 + nf*16 + lm][ks*32 + lg*8];
                bl[nf] = *(const short8*)&Bl[wc*64 + nf*16 + lm][ks*32 + lg*8];
            }
            #pragma unroll
            for (int mf = 0; mf < 4; mf++)
                #pragma unroll
                for (int nf = 0; nf < 4; nf++){
                    acc[mf][nf] = __builtin_amdgcn_mfma_f32_16x16x32_bf16(ah[mf], bh[nf], acc[mf][nf], 0, 0, 0);
                    acc[mf][nf] = __builtin_amdgcn_mfma_f32_16x16x32_bf16(al[mf], bh[nf], acc[mf][nf], 0, 0, 0);
                    acc[mf][nf] = __builtin_amdgcn_mfma_f32_16x16x32_bf16(ah[mf], bl[nf], acc[mf][nf], 0, 0, 0);
                }
        }
        __syncthreads();
    }
    #pragma unroll
    for (int nf = 0; nf < 4; nf++){
        int col = colBase + wc*64 + nf*16 + lm;
        float bv = bias[col];
        #pragma unroll
        for (int mf = 0; mf < 4; mf++){
            int row = rowBase + wr*64 + mf*16 + lg*4;
            #pragma unroll
            for (int j = 0; j < 4; j++){
                float o = acc[mf][nf][j] + bv;
                if (ACT) o = fmaxf(o, 0.f);
                C[(size_t)(row + j)*Nout + col] = o;
            }
        }
    }
}

// ---------------- BatchNorm ----------------
__global__ __launch_bounds__(256) void bn_stats_kernel(const float* __restrict__ A,
        float* __restrict__ sums, int n){
    int c = threadIdx.x;
    int r0 = blockIdx.x*128, r1 = min(n, r0+128);
    float s0=0.f, s1=0.f, q0=0.f, q1=0.f;
    for (int r = r0; r < r1; r++){
        float v0 = A[(size_t)r*D + c];
        float v1 = A[(size_t)r*D + 256 + c];
        s0 += v0; q0 += v0*v0; s1 += v1; q1 += v1*v1;
    }
    atomicAdd(&sums[c], s0);
    atomicAdd(&sums[c+256], s1);
    atomicAdd(&sums[512+c], q0);
    atomicAdd(&sums[512+c+256], q1);
}

__global__ void bn_final_kernel(const float* __restrict__ sums, const float* __restrict__ gamma,
        const float* __restrict__ beta, float* __restrict__ sc, int n){
    int c = threadIdx.x;
    float mean = sums[c] / (float)n;
    float var = sums[512+c] / (float)n - mean*mean;
    float r = rsqrtf(var + 1e-5f);
    float scale = r * gamma[c];
    sc[c] = scale;
    sc[512+c] = beta[c] - mean*scale;
}

__global__ void bn_apply_kernel(const float* __restrict__ in, const float* __restrict__ sc,
        float* __restrict__ out, int total4){
    int i = blockIdx.x*256 + threadIdx.x;
    if (i >= total4) return;
    int c4 = (i*4) & (D-1);
    float4 vv = *(const float4*)(in + (size_t)i*4);
    float4 s  = *(const float4*)(sc + c4);
    float4 sh = *(const float4*)(sc + 512 + c4);
    float4 o;
    o.x = vv.x*s.x + sh.x; o.y = vv.y*s.y + sh.y;
    o.z = vv.z*s.z + sh.z; o.w = vv.w*s.w + sh.w;
    *(float4*)(out + (size_t)i*4) = o;
}

// ---------------- ragged masked flash attention (f32, round-2-proven) ----------------
__global__ __launch_bounds__(256) void attn_kernel(const float* __restrict__ qk,
        const float* __restrict__ v, const unsigned char* __restrict__ mask,
        const int* __restrict__ ptr, float* __restrict__ out, int N){
    __shared__ float Kt[64][65];
    __shared__ float Vs[64][68];
    __shared__ float Qs[16][68];
    __shared__ float Ps[4][64];
    int b = blockIdx.z, h = blockIdx.y;
    int base = ptr[b];
    int size = ptr[b+1] - base;
    if (base < 0) base = 0; if (base > N) base = N;
    if (size < 0) size = 0; if (size > N - base) size = N - base;
    int rowBase = blockIdx.x * 16;
    if (rowBase >= size) return;
    int tid = threadIdx.x;
    int w = tid >> 6, lane = tid & 63;
    {
        int rl = tid >> 4, c4 = (tid & 15) * 4;
        int r = rowBase + rl;
        float4 q4 = make_float4(0.f, 0.f, 0.f, 0.f);
        if (r < size)
            q4 = *(const float4*)(qk + (size_t)(base + r)*1024 + 512 + h*64 + c4);
        *(float4*)&Qs[rl][c4] = q4;
    }
    float m[4], l[4], acc[4];
    #pragma unroll
    for (int i = 0; i < 4; i++){ m[i] = -INFINITY; l[i] = 0.f; acc[i] = 0.f; }
    int nt = (size + 63) >> 6;
    for (int t = 0; t < nt; t++){
        int jBase = t * 64;
        __syncthreads();
        #pragma unroll
        for (int p = 0; p < 4; p++){
            int idx = tid + p*256;
            int rl = idx >> 4, c4 = (idx & 15) * 4;
            int j = jBase + rl;
            float4 kk = make_float4(0.f,0.f,0.f,0.f), vv = make_float4(0.f,0.f,0.f,0.f);
            if (j < size){
                size_t node = (size_t)(base + j);
                kk = *(const float4*)(qk + node*1024 + h*64 + c4);
                vv = *(const float4*)(v  + node*512  + h*64 + c4);
            }
            Kt[c4+0][rl] = kk.x; Kt[c4+1][rl] = kk.y;
            Kt[c4+2][rl] = kk.z; Kt[c4+3][rl] = kk.w;
            *(float4*)&Vs[rl][c4] = vv;
        }
        __syncthreads();
        for (int ri = 0; ri < 4; ri++){
            int r = rowBase + w*4 + ri;
            if (r >= size) continue;
            int j = jBase + lane;
            float s = -INFINITY;
            if (j < size && !mask[((size_t)b*LMAX + r)*LMAX + j]){
                float dot = 0.f;
                const float* qrow = Qs[w*4 + ri];
                #pragma unroll
                for (int d = 0; d < 64; d++) dot += qrow[d] * Kt[d][lane];
                s = dot * 0.125f;
            }
            float tm = s;
            #pragma unroll
            for (int off = 32; off > 0; off >>= 1) tm = fmaxf(tm, __shfl_xor(tm, off));
            if (tm == -INFINITY) continue;
            float mnew = fmaxf(m[ri], tm);
            float alpha = __expf(m[ri] - mnew);
            float p = (s == -INFINITY) ? 0.f : __expf(s - mnew);
            float psum = p;
            #pragma unroll
            for (int off = 32; off > 0; off >>= 1) psum += __shfl_xor(psum, off);
            m[ri] = mnew;
            l[ri] = l[ri]*alpha + psum;
            Ps[w][lane] = p;
            float a2 = 0.f;
            #pragma unroll
            for (int jj = 0; jj < 64; jj++) a2 += Ps[w][jj] * Vs[jj][lane];
            acc[ri] = acc[ri]*alpha + a2;
        }
    }
    #pragma unroll
    for (int ri = 0; ri < 4; ri++){
        int r = rowBase + w*4 + ri;
        if (r < size) out[(size_t)(base + r)*512 + h*64 + lane] = acc[ri] / l[ri];
    }
}

extern "C" void kernel_launch(void* const* d_in, const int* in_sizes, int n_in,
                              void* d_out, int out_size, void* d_ws, size_t ws_size,
                              hipStream_t stream){
    const float* x        = (const float*)d_in[0];
    const int*   ei_raw   = (const int*)d_in[1];
    const unsigned char* mask_raw = (const unsigned char*)d_in[2];
    const int*   ptr_raw  = (const int*)d_in[3];
    const float* gin_w1   = (const float*)d_in[4];
    const float* gin_b1   = (const float*)d_in[5];
    const float* gin_w2   = (const float*)d_in[6];
    const float* gin_b2   = (const float*)d_in[7];
    const float* bn_gamma = (const float*)d_in[8];
    const float* bn_beta  = (const float*)d_in[9];
    const float* se_w     = (const float*)d_in[10];
    const float* se_b     = (const float*)d_in[11];
    const float* qk_w     = (const float*)d_in[12];
    const float* qk_b     = (const float*)d_in[13];
    const float* v_w      = (const float*)d_in[14];
    const float* v_b      = (const float*)d_in[15];
    const float* out_w    = (const float*)d_in[16];
    const float* out_b    = (const float*)d_in[17];

    const int N  = in_sizes[0] / D;       // 12160
    const int E  = in_sizes[1] / 2;       // 97280
    const int B  = in_sizes[3] - 1;       // 32
    const int Mn = in_sizes[2];           // B*512*512

    char* ws = (char*)d_ws;
    size_t NB = (size_t)N * D * sizeof(float);
    float* vbuf  = (float*)(ws);
    float* bufA  = (float*)(ws + NB);
    float* bufB  = (float*)(ws + 2*NB);
    float* bufC  = (float*)(ws + 3*NB);
    float* qkbuf = bufA;                   // spans [NB, 3NB) when A/B are dead
    char* p = ws + 4*NB;
    auto alloc = [&](size_t bytes) -> char* {
        char* q = p; p += (bytes + 255) & ~(size_t)255; return q;
    };
    float* sums   = (float*)alloc(1024*sizeof(float));
    float* sc     = (float*)alloc(1024*sizeof(float));
    int*   flags  = (int*)alloc(16*sizeof(int));
    int*   deg    = (int*)alloc((size_t)N*sizeof(int));
    int*   offs   = (int*)alloc((size_t)(N+1)*sizeof(int));
    int*   cursor = (int*)alloc((size_t)N*sizeof(int));
    int*   in_src = (int*)alloc((size_t)E*sizeof(int));
    int*   ptr32  = (int*)alloc(64*sizeof(int));
    int*   ei32   = (int*)alloc((size_t)2*E*sizeof(int));
    unsigned char* mask8 = (unsigned char*)alloc((size_t)Mn);
    u16*   wtsh   = (u16*)alloc((size_t)2883584*sizeof(u16));   // 11 x 512x512 slots (hi)
    u16*   wtsl   = (u16*)alloc((size_t)2883584*sizeof(u16));   // lo
    const size_t SLOT = 262144;
    u16 *wh_v = wtsh, *wl_v = wtsl;
    u16 *wh_g[6], *wl_g[6];
    for (int i = 0; i < 6; i++){ wh_g[i] = wtsh + SLOT*(1+i); wl_g[i] = wtsl + SLOT*(1+i); }
    u16 *wh_se  = wtsh + SLOT*7,  *wl_se  = wtsl + SLOT*7;
    u16 *wh_qk  = wtsh + SLOT*8,  *wl_qk  = wtsl + SLOT*8;   // 2 slots
    u16 *wh_out = wtsh + SLOT*10, *wl_out = wtsl + SLOT*10;

    // --- dtype probe + normalization ---
    probe_kernel<<<1, 64, 0, stream>>>(ptr_raw, mask_raw, flags);
    conv_int_kernel<<<1, 64, 0, stream>>>(ptr_raw, ptr32, flags, B + 1);
    conv_int_kernel<<<(2*E + 255)/256, 256, 0, stream>>>(ei_raw, ei32, flags, 2*E);
    conv_mask_kernel<<<(Mn + 255)/256, 256, 0, stream>>>(mask_raw, mask8, flags, Mn);

    // --- CSR inversion ---
    hipMemsetAsync(deg, 0, (size_t)N*sizeof(int), stream);
    hipMemsetAsync(cursor, 0, (size_t)N*sizeof(int), stream);
    count_kernel<<<(E+255)/256, 256, 0, stream>>>(ei32, deg, E, N);
    scan_kernel<<<1, 1024, 0, stream>>>(deg, offs, N);
    fill_kernel<<<(E+255)/256, 256, 0, stream>>>(ei32, offs, cursor, in_src, E, N);

    // --- weight transpose + split convert ---
    transpose_kernel<<<dim3(16,16), 256, 0, stream>>>(v_w, wh_v, wl_v, D, D);
    for (int i = 0; i < NGIN; i++){
        transpose_kernel<<<dim3(16,16), 256, 0, stream>>>(gin_w1 + (size_t)i*D*D, wh_g[2*i],   wl_g[2*i],   D, D);
        transpose_kernel<<<dim3(16,16), 256, 0, stream>>>(gin_w2 + (size_t)i*D*D, wh_g[2*i+1], wl_g[2*i+1], D, D);
    }
    transpose_kernel<<<dim3(16,16), 256, 0, stream>>>(se_w,  wh_se,  wl_se,  D, D);
    transpose_kernel<<<dim3(32,16), 256, 0, stream>>>(qk_w,  wh_qk,  wl_qk,  D, 2*D);
    transpose_kernel<<<dim3(16,16), 256, 0, stream>>>(out_w, wh_out, wl_out, D, D);

    dim3 g512(4, N/128), g1024(8, N/128);

    // v = x @ v_w + v_b
    gemm_mfma<0><<<g512, 256, 0, stream>>>(x, wh_v, wl_v, v_b, vbuf, D, D);

    // GIN layers
    const float* h = x;
    for (int i = 0; i < NGIN; i++){
        gather_kernel<<<N, 256, 0, stream>>>(h, offs, in_src, bufB);
        gemm_mfma<1><<<g512, 256, 0, stream>>>(bufB, wh_g[2*i],   wl_g[2*i],   gin_b1 + (size_t)i*D, bufC, D, D);
        gemm_mfma<1><<<g512, 256, 0, stream>>>(bufC, wh_g[2*i+1], wl_g[2*i+1], gin_b2 + (size_t)i*D, bufA, D, D);
        h = bufA;
    }

    // BatchNorm (batch stats, biased var)
    hipMemsetAsync(sums, 0, 1024*sizeof(float), stream);
    bn_stats_kernel<<<(N+127)/128, 256, 0, stream>>>(bufA, sums, N);
    bn_final_kernel<<<1, 512, 0, stream>>>(sums, bn_gamma, bn_beta, sc, N);
    bn_apply_kernel<<<(N*D/4 + 255)/256, 256, 0, stream>>>(bufA, sc, bufB, N*D/4);

    // x_struct = bn(h) @ se_w + se_b
    gemm_mfma<0><<<g512, 256, 0, stream>>>(bufB, wh_se, wl_se, se_b, bufC, D, D);

    // qk = x_struct @ qk_w + qk_b
    gemm_mfma<0><<<g1024, 256, 0, stream>>>(bufC, wh_qk, wl_qk, qk_b, qkbuf, D, 2*D);

    // attention -> bufC (f32, proven)
    attn_kernel<<<dim3(LMAX/16, NHEAD, B), 256, 0, stream>>>(qkbuf, vbuf, mask8, ptr32, bufC, N);

    // out = attn_out @ out_w + out_b
    gemm_mfma<0><<<g512, 256, 0, stream>>>(bufC, wh_out, wl_out, out_b, (float*)d_out, D, D);
}

// Round 7
// 717.052 us; speedup vs baseline: 4.3280x; 1.8570x over previous
//
#include <hip/hip_runtime.h>
#include <hip/hip_bf16.h>
#include <cstdint>
#include <cstddef>

#define D 512
#define NHEAD 8
#define LMAX 512
#define NGIN 3

typedef unsigned short u16;
typedef unsigned long long u64;
typedef __attribute__((ext_vector_type(8))) short short8;
typedef __attribute__((ext_vector_type(8))) unsigned short ushort8;
typedef __attribute__((ext_vector_type(4))) float f32x4;

static __device__ inline u16 f2bf(float f){
    union { float f; uint32_t u; } c; c.f = f;
    uint32_t r = (c.u + 0x7fffu + ((c.u >> 16) & 1u)) >> 16;
    return (u16)r;
}
static __device__ inline float bf2f(u16 h){
    union { uint32_t u; float f; } c; c.u = ((uint32_t)h) << 16; return c.f;
}

// ---------------- dtype probe + normalization ----------------
__global__ void probe_kernel(const int* __restrict__ ptr_raw,
                             const unsigned char* __restrict__ mask_raw,
                             int* __restrict__ flags){
    if (threadIdx.x == 0){
        flags[0] = (ptr_raw[1] == 0) ? 1 : 0;
        int cntOdd = 0, cnt4 = 0;
        for (int i = 1; i < 2048; i += 2) cntOdd += (mask_raw[i] != 0);
        for (int i = 4; i < 2048; i += 8) cnt4   += (mask_raw[i] != 0);
        flags[1] = (cntOdd > 64) ? 1 : ((cnt4 > 16) ? 4 : 8);
    }
}

__global__ void conv_int_kernel(const int* __restrict__ raw, int* __restrict__ outp,
                                const int* __restrict__ flags, int n){
    int i = blockIdx.x*256 + threadIdx.x;
    if (i < n) outp[i] = flags[0] ? raw[2*i] : raw[i];
}

// pack DAG mask into bits: maskbits[(b*512 + r)*8 + t] bit j = mask[b][r][t*64+j]
__global__ void maskbits_kernel(const unsigned char* __restrict__ raw,
                                u64* __restrict__ outp,
                                const int* __restrict__ flags, int total){
    int idx = blockIdx.x*256 + threadIdx.x;
    if (idx >= total) return;
    int w = flags[1];
    size_t ebase = (size_t)(idx >> 3) * 512 + (size_t)(idx & 7) * 64;
    u64 bits = 0;
    if (w == 1){
        const u64* p8 = (const u64*)(raw + ebase);
        #pragma unroll
        for (int g = 0; g < 8; g++){
            u64 v = p8[g];
            #pragma unroll
            for (int by = 0; by < 8; by++)
                if ((v >> (by*8)) & 0xffull) bits |= 1ull << (g*8 + by);
        }
    } else {
        for (int j = 0; j < 64; j++)
            if (raw[(ebase + j) * (size_t)w]) bits |= 1ull << j;
    }
    outp[idx] = bits;
}

// ---------------- CSR inversion ----------------
__global__ void count_kernel(const int* __restrict__ ei, int* __restrict__ deg, int E, int N){
    int e = blockIdx.x*256 + threadIdx.x;
    if (e < E){
        int d = ei[E + e];
        if ((unsigned)d < (unsigned)N) atomicAdd(&deg[d], 1);
    }
}

__global__ void scan_kernel(const int* __restrict__ deg, int* __restrict__ offs, int n){
    __shared__ int buf[1024];
    __shared__ int carry_s;
    int tid = threadIdx.x;
    if (tid == 0){ carry_s = 0; offs[0] = 0; }
    __syncthreads();
    int nChunks = (n + 1023) / 1024;
    for (int ch = 0; ch < nChunks; ch++){
        int i = ch*1024 + tid;
        int val = (i < n) ? deg[i] : 0;
        buf[tid] = val;
        __syncthreads();
        for (int off = 1; off < 1024; off <<= 1){
            int t = (tid >= off) ? buf[tid - off] : 0;
            __syncthreads();
            buf[tid] += t;
            __syncthreads();
        }
        if (i < n) offs[i+1] = carry_s + buf[tid];
        __syncthreads();
        if (tid == 0) carry_s += buf[1023];
        __syncthreads();
    }
}

__global__ void fill_kernel(const int* __restrict__ ei, const int* __restrict__ offs,
                            int* __restrict__ cursor, int* __restrict__ in_src, int E, int N){
    int e = blockIdx.x*256 + threadIdx.x;
    if (e < E){
        int d = ei[E + e];
        if ((unsigned)d < (unsigned)N){
            int slot = atomicAdd(&cursor[d], 1);
            in_src[offs[d] + slot] = ei[e];
        }
    }
}

// ---------------- gather ----------------
__global__ __launch_bounds__(256) void gather_kernel(const float* __restrict__ h,
        const int* __restrict__ offs, const int* __restrict__ in_src,
        float* __restrict__ out){
    int node = blockIdx.x;
    int tid = threadIdx.x;
    const float* hr = h + (size_t)node*D;
    float a0 = hr[tid], a1 = hr[tid+256];
    int s = offs[node], e = offs[node+1];
    for (int i = s; i < e; i++){
        const float* hs = h + (size_t)in_src[i]*D;
        a0 += hs[tid]; a1 += hs[tid+256];
    }
    float* orow = out + (size_t)node*D;
    orow[tid] = a0; orow[tid+256] = a1;
}

// ---------------- weight transpose + split-bf16 convert ----------------
__global__ __launch_bounds__(256) void transpose_kernel(const float* __restrict__ W,
        u16* __restrict__ Wh, u16* __restrict__ Wl, int K, int Nout){
    __shared__ float T[32][33];
    int nb = blockIdx.x*32, kb = blockIdx.y*32;
    int ln = threadIdx.x & 31, lk = threadIdx.x >> 5;
    #pragma unroll
    for (int i = 0; i < 4; i++)
        T[lk + 8*i][ln] = W[(size_t)(kb + lk + 8*i)*Nout + nb + ln];
    __syncthreads();
    #pragma unroll
    for (int i = 0; i < 4; i++){
        float val = T[ln][lk + 8*i];
        u16 h = f2bf(val);
        size_t idx = (size_t)(nb + lk + 8*i)*K + kb + ln;
        Wh[idx] = h;
        Wl[idx] = f2bf(val - bf2f(h));
    }
}

// ---------------- split-bf16 MFMA GEMM (round-5/6 verified) ----------------
#define GS 72
template<int ACT>
__global__ __launch_bounds__(256) void gemm_mfma(const float* __restrict__ A,
        const u16* __restrict__ Wth, const u16* __restrict__ Wtl,
        const float* __restrict__ bias,
        float* __restrict__ C, int K, int Nout){
    __shared__ u16 Ah[128][GS];
    __shared__ u16 Al[128][GS];
    __shared__ u16 Bh[128][GS];
    __shared__ u16 Bl[128][GS];
    int tid = threadIdx.x;
    int rowBase = blockIdx.y*128, colBase = blockIdx.x*128;
    int w = tid >> 6, l = tid & 63, lg = l >> 4, lm = l & 15;
    int wr = w >> 1, wc = w & 1;
    f32x4 acc[4][4] = {};
    int sr = tid >> 1, skb = (tid & 1)*32;
    const float* Ap  = A   + (size_t)(rowBase + sr)*K + skb;
    const u16*  Wph = Wth + (size_t)(colBase + sr)*K + skb;
    const u16*  Wpl = Wtl + (size_t)(colBase + sr)*K + skb;
    for (int k0 = 0; k0 < K; k0 += 64){
        #pragma unroll
        for (int i = 0; i < 4; i++){
            float4 f0 = *(const float4*)(Ap + k0 + i*8);
            float4 f1 = *(const float4*)(Ap + k0 + i*8 + 4);
            float fv[8] = {f0.x,f0.y,f0.z,f0.w,f1.x,f1.y,f1.z,f1.w};
            ushort8 ph, pl;
            #pragma unroll
            for (int j = 0; j < 8; j++){
                u16 hh = f2bf(fv[j]);
                ph[j] = hh;
                pl[j] = f2bf(fv[j] - bf2f(hh));
            }
            *(ushort8*)&Ah[sr][skb + i*8] = ph;
            *(ushort8*)&Al[sr][skb + i*8] = pl;
        }
        #pragma unroll
        for (int i = 0; i < 4; i++){
            *(ushort8*)&Bh[sr][skb + i*8] = *(const ushort8*)(Wph + k0 + i*8);
            *(ushort8*)&Bl[sr][skb + i*8] = *(const ushort8*)(Wpl + k0 + i*8);
        }
        __syncthreads();
        #pragma unroll
        for (int ks = 0; ks < 2; ks++){
            short8 ah[4], al[4], bh[4], bl[4];
            #pragma unroll
            for (int mf = 0; mf < 4; mf++){
                ah[mf] = *(const short8*)&Ah[wr*64 + mf*16 + lm][ks*32 + lg*8];
                al[mf] = *(const short8*)&Al[wr*64 + mf*16 + lm][ks*32 + lg*8];
            }
            #pragma unroll
            for (int nf = 0; nf < 4; nf++){
                bh[nf] = *(const short8*)&Bh[wc*64 + nf*16 + lm][ks*32 + lg*8];
                bl[nf] = *(const short8*)&Bl[wc*64 + nf*16 + lm][ks*32 + lg*8];
            }
            #pragma unroll
            for (int mf = 0; mf < 4; mf++)
                #pragma unroll
                for (int nf = 0; nf < 4; nf++){
                    acc[mf][nf] = __builtin_amdgcn_mfma_f32_16x16x32_bf16(ah[mf], bh[nf], acc[mf][nf], 0, 0, 0);
                    acc[mf][nf] = __builtin_amdgcn_mfma_f32_16x16x32_bf16(al[mf], bh[nf], acc[mf][nf], 0, 0, 0);
                    acc[mf][nf] = __builtin_amdgcn_mfma_f32_16x16x32_bf16(ah[mf], bl[nf], acc[mf][nf], 0, 0, 0);
                }
        }
        __syncthreads();
    }
    #pragma unroll
    for (int nf = 0; nf < 4; nf++){
        int col = colBase + wc*64 + nf*16 + lm;
        float bv = bias[col];
        #pragma unroll
        for (int mf = 0; mf < 4; mf++){
            int row = rowBase + wr*64 + mf*16 + lg*4;
            #pragma unroll
            for (int j = 0; j < 4; j++){
                float o = acc[mf][nf][j] + bv;
                if (ACT) o = fmaxf(o, 0.f);
                C[(size_t)(row + j)*Nout + col] = o;
            }
        }
    }
}

// ---------------- BatchNorm ----------------
__global__ __launch_bounds__(256) void bn_stats_kernel(const float* __restrict__ A,
        float* __restrict__ sums, int n){
    int c = threadIdx.x;
    int r0 = blockIdx.x*128, r1 = min(n, r0+128);
    float s0=0.f, s1=0.f, q0=0.f, q1=0.f;
    for (int r = r0; r < r1; r++){
        float v0 = A[(size_t)r*D + c];
        float v1 = A[(size_t)r*D + 256 + c];
        s0 += v0; q0 += v0*v0; s1 += v1; q1 += v1*v1;
    }
    atomicAdd(&sums[c], s0);
    atomicAdd(&sums[c+256], s1);
    atomicAdd(&sums[512+c], q0);
    atomicAdd(&sums[512+c+256], q1);
}

__global__ void bn_final_kernel(const float* __restrict__ sums, const float* __restrict__ gamma,
        const float* __restrict__ beta, float* __restrict__ sc, int n){
    int c = threadIdx.x;
    float mean = sums[c] / (float)n;
    float var = sums[512+c] / (float)n - mean*mean;
    float r = rsqrtf(var + 1e-5f);
    float scale = r * gamma[c];
    sc[c] = scale;
    sc[512+c] = beta[c] - mean*scale;
}

__global__ void bn_apply_kernel(const float* __restrict__ in, const float* __restrict__ sc,
        float* __restrict__ out, int total4){
    int i = blockIdx.x*256 + threadIdx.x;
    if (i >= total4) return;
    int c4 = (i*4) & (D-1);
    float4 vv = *(const float4*)(in + (size_t)i*4);
    float4 s  = *(const float4*)(sc + c4);
    float4 sh = *(const float4*)(sc + 512 + c4);
    float4 o;
    o.x = vv.x*s.x + sh.x; o.y = vv.y*s.y + sh.y;
    o.z = vv.z*s.z + sh.z; o.w = vv.w*s.w + sh.w;
    *(float4*)(out + (size_t)i*4) = o;
}

// ---------------- MFMA ragged masked flash attention (split-bf16 QK^T) ----------------
// grid (LMAX/64, NHEAD, B), 256 threads = 4 waves; wave w owns q-rows q0+w*16..+15.
// Reads f32 qk [N][1024] (K cols 0..511, Q cols 512..1023) and f32 v [N][512].
#define ATS 72
__global__ __launch_bounds__(256) void attn_mfma_kernel(const float* __restrict__ qk,
        const float* __restrict__ v, const u64* __restrict__ maskbits,
        const int* __restrict__ ptr, float* __restrict__ outp, int N){
    __shared__ u16 Kh[64][ATS];       // [key][d] hi
    __shared__ u16 Kl[64][ATS];       // [key][d] lo
    __shared__ u16 Vt[64][ATS];       // [d][key]
    __shared__ u16 Pl[4][16][ATS];    // per-wave P [qrow][key]
    int b = blockIdx.z, h = blockIdx.y;
    int base = ptr[b], size = ptr[b+1] - base;
    int q0 = blockIdx.x * 64;
    if (q0 >= size) return;
    int tid = threadIdx.x, w = tid >> 6, l = tid & 63;
    int lg = l >> 4, lm = l & 15;
    // Q fragments (split hi/lo): row = q0 + w*16 + lm, k-range = ks*32 + lg*8
    short8 qh[2], ql[2];
    {
        int qrow = q0 + w*16 + lm;
        int qr = (qrow < size) ? qrow : 0;
        const float* qp = qk + (size_t)(base + qr)*1024 + 512 + h*64;
        #pragma unroll
        for (int ks = 0; ks < 2; ks++){
            float4 f0 = *(const float4*)(qp + ks*32 + lg*8);
            float4 f1 = *(const float4*)(qp + ks*32 + lg*8 + 4);
            float fv[8] = {f0.x,f0.y,f0.z,f0.w,f1.x,f1.y,f1.z,f1.w};
            #pragma unroll
            for (int j = 0; j < 8; j++){
                float val = (qrow < size) ? fv[j] : 0.f;
                u16 hh = f2bf(val);
                ((u16*)&qh[ks])[j] = hh;
                ((u16*)&ql[ks])[j] = f2bf(val - bf2f(hh));
            }
        }
    }
    f32x4 acco[4] = {};
    float mrow[4], lrow[4];
    #pragma unroll
    for (int j = 0; j < 4; j++){ mrow[j] = -INFINITY; lrow[j] = 0.f; }
    int nt = (size + 63) >> 6;
    for (int t = 0; t < nt; t++){
        int j0 = t*64;
        __syncthreads();
        {   // stage K (split, natural) and V (plain, transposed); wave w covers d-range w*16..+15
            int jj = tid & 63, db = (tid >> 6)*16;
            int key = j0 + jj;
            bool ok = key < size;
            const float* kp = qk + (size_t)(base + (ok ? key : 0))*1024 + h*64 + db;
            const float* vp = v  + (size_t)(base + (ok ? key : 0))*512  + h*64 + db;
            ushort8 kh0, kh1, kl0, kl1;
            #pragma unroll
            for (int half = 0; half < 2; half++){
                float4 f0 = ok ? *(const float4*)(kp + half*8)     : make_float4(0,0,0,0);
                float4 f1 = ok ? *(const float4*)(kp + half*8 + 4) : make_float4(0,0,0,0);
                float fv[8] = {f0.x,f0.y,f0.z,f0.w,f1.x,f1.y,f1.z,f1.w};
                #pragma unroll
                for (int j = 0; j < 8; j++){
                    u16 hh = f2bf(fv[j]);
                    if (half == 0){ kh0[j] = hh; kl0[j] = f2bf(fv[j] - bf2f(hh)); }
                    else          { kh1[j] = hh; kl1[j] = f2bf(fv[j] - bf2f(hh)); }
                }
            }
            *(ushort8*)&Kh[jj][db]     = kh0;
            *(ushort8*)&Kh[jj][db + 8] = kh1;
            *(ushort8*)&Kl[jj][db]     = kl0;
            *(ushort8*)&Kl[jj][db + 8] = kl1;
            float4 v0 = ok ? *(const float4*)(vp)      : make_float4(0,0,0,0);
            float4 v1 = ok ? *(const float4*)(vp + 4)  : make_float4(0,0,0,0);
            float4 v2 = ok ? *(const float4*)(vp + 8)  : make_float4(0,0,0,0);
            float4 v3 = ok ? *(const float4*)(vp + 12) : make_float4(0,0,0,0);
            float va[16] = {v0.x,v0.y,v0.z,v0.w,v1.x,v1.y,v1.z,v1.w,
                            v2.x,v2.y,v2.z,v2.w,v3.x,v3.y,v3.z,v3.w};
            #pragma unroll
            for (int i = 0; i < 16; i++) Vt[db + i][jj] = f2bf(va[i]);
        }
        __syncthreads();
        // QK^T (3-term split) -> sc: rows = q (lg*4+j), cols = keys (nf*16+lm)
        f32x4 sc[4] = {};
        #pragma unroll
        for (int nf = 0; nf < 4; nf++)
            #pragma unroll
            for (int ks = 0; ks < 2; ks++){
                short8 kh = *(const short8*)&Kh[nf*16 + lm][ks*32 + lg*8];
                short8 kl = *(const short8*)&Kl[nf*16 + lm][ks*32 + lg*8];
                sc[nf] = __builtin_amdgcn_mfma_f32_16x16x32_bf16(qh[ks], kh, sc[nf], 0, 0, 0);
                sc[nf] = __builtin_amdgcn_mfma_f32_16x16x32_bf16(ql[ks], kh, sc[nf], 0, 0, 0);
                sc[nf] = __builtin_amdgcn_mfma_f32_16x16x32_bf16(qh[ks], kl, sc[nf], 0, 0, 0);
            }
        // mask + online softmax
        u64 mb[4];
        #pragma unroll
        for (int j = 0; j < 4; j++)
            mb[j] = maskbits[((size_t)b*LMAX + (q0 + w*16 + lg*4 + j))*8 + t];
        float mx[4], alpha[4];
        #pragma unroll
        for (int j = 0; j < 4; j++){
            float s0 = -INFINITY;
            #pragma unroll
            for (int nf = 0; nf < 4; nf++){
                int key = j0 + nf*16 + lm;
                float s = sc[nf][j] * 0.125f;
                bool msk = (key >= size) || ((mb[j] >> (nf*16 + lm)) & 1);
                s = msk ? -INFINITY : s;
                sc[nf][j] = s;
                s0 = fmaxf(s0, s);
            }
            #pragma unroll
            for (int off = 1; off < 16; off <<= 1) s0 = fmaxf(s0, __shfl_xor(s0, off));
            mx[j] = s0;
        }
        #pragma unroll
        for (int j = 0; j < 4; j++){
            if (mx[j] == -INFINITY){ alpha[j] = 1.f; }
            else {
                float mn = fmaxf(mrow[j], mx[j]);
                alpha[j] = __expf(mrow[j] - mn);   // exp(-inf)=0 on first finite tile
                mrow[j] = mn;
            }
        }
        float ps[4] = {0.f, 0.f, 0.f, 0.f};
        #pragma unroll
        for (int nf = 0; nf < 4; nf++)
            #pragma unroll
            for (int j = 0; j < 4; j++){
                float p = (mx[j] == -INFINITY) ? 0.f : __expf(sc[nf][j] - mrow[j]);
                ps[j] += p;
                Pl[w][lg*4 + j][nf*16 + lm] = f2bf(p);
            }
        #pragma unroll
        for (int j = 0; j < 4; j++){
            float s = ps[j];
            #pragma unroll
            for (int off = 1; off < 16; off <<= 1) s += __shfl_xor(s, off);
            lrow[j] = lrow[j]*alpha[j] + s;
        }
        #pragma unroll
        for (int df = 0; df < 4; df++)
            #pragma unroll
            for (int j = 0; j < 4; j++) acco[df][j] *= alpha[j];
        // PV: A = P (row=q, k=key), B = Vt (col=d, k=key)
        #pragma unroll
        for (int ks = 0; ks < 2; ks++){
            short8 pf = *(const short8*)&Pl[w][lm][ks*32 + lg*8];
            #pragma unroll
            for (int df = 0; df < 4; df++){
                short8 vf = *(const short8*)&Vt[df*16 + lm][ks*32 + lg*8];
                acco[df] = __builtin_amdgcn_mfma_f32_16x16x32_bf16(pf, vf, acco[df], 0, 0, 0);
            }
        }
    }
    #pragma unroll
    for (int j = 0; j < 4; j++){
        int r = q0 + w*16 + lg*4 + j;
        if (r < size){
            float inv = 1.f / lrow[j];
            #pragma unroll
            for (int df = 0; df < 4; df++)
                outp[(size_t)(base + r)*D + h*64 + df*16 + lm] = acco[df][j] * inv;
        }
    }
}

extern "C" void kernel_launch(void* const* d_in, const int* in_sizes, int n_in,
                              void* d_out, int out_size, void* d_ws, size_t ws_size,
                              hipStream_t stream){
    const float* x        = (const float*)d_in[0];
    const int*   ei_raw   = (const int*)d_in[1];
    const unsigned char* mask_raw = (const unsigned char*)d_in[2];
    const int*   ptr_raw  = (const int*)d_in[3];
    const float* gin_w1   = (const float*)d_in[4];
    const float* gin_b1   = (const float*)d_in[5];
    const float* gin_w2   = (const float*)d_in[6];
    const float* gin_b2   = (const float*)d_in[7];
    const float* bn_gamma = (const float*)d_in[8];
    const float* bn_beta  = (const float*)d_in[9];
    const float* se_w     = (const float*)d_in[10];
    const float* se_b     = (const float*)d_in[11];
    const float* qk_w     = (const float*)d_in[12];
    const float* qk_b     = (const float*)d_in[13];
    const float* v_w      = (const float*)d_in[14];
    const float* v_b      = (const float*)d_in[15];
    const float* out_w    = (const float*)d_in[16];
    const float* out_b    = (const float*)d_in[17];

    const int N  = in_sizes[0] / D;       // 12160
    const int E  = in_sizes[1] / 2;       // 97280
    const int B  = in_sizes[3] - 1;       // 32
    const int Mn = in_sizes[2];           // B*512*512

    char* ws = (char*)d_ws;
    size_t NB = (size_t)N * D * sizeof(float);
    float* vbuf  = (float*)(ws);
    float* bufA  = (float*)(ws + NB);
    float* bufB  = (float*)(ws + 2*NB);
    float* bufC  = (float*)(ws + 3*NB);
    float* qkbuf = bufA;                   // spans [NB, 3NB) when A/B are dead
    char* p = ws + 4*NB;
    auto alloc = [&](size_t bytes) -> char* {
        char* q = p; p += (bytes + 255) & ~(size_t)255; return q;
    };
    float* sums   = (float*)alloc(1024*sizeof(float));
    float* sc     = (float*)alloc(1024*sizeof(float));
    int*   flags  = (int*)alloc(16*sizeof(int));
    int*   deg    = (int*)alloc((size_t)N*sizeof(int));
    int*   offs   = (int*)alloc((size_t)(N+1)*sizeof(int));
    int*   cursor = (int*)alloc((size_t)N*sizeof(int));
    int*   in_src = (int*)alloc((size_t)E*sizeof(int));
    int*   ptr32  = (int*)alloc(64*sizeof(int));
    int*   ei32   = (int*)alloc((size_t)2*E*sizeof(int));
    u64*   mbits  = (u64*)alloc((size_t)(Mn/64)*sizeof(u64));
    u16*   wtsh   = (u16*)alloc((size_t)2883584*sizeof(u16));   // 11 x 512x512 slots (hi)
    u16*   wtsl   = (u16*)alloc((size_t)2883584*sizeof(u16));   // lo
    const size_t SLOT = 262144;
    u16 *wh_v = wtsh, *wl_v = wtsl;
    u16 *wh_g[6], *wl_g[6];
    for (int i = 0; i < 6; i++){ wh_g[i] = wtsh + SLOT*(1+i); wl_g[i] = wtsl + SLOT*(1+i); }
    u16 *wh_se  = wtsh + SLOT*7,  *wl_se  = wtsl + SLOT*7;
    u16 *wh_qk  = wtsh + SLOT*8,  *wl_qk  = wtsl + SLOT*8;   // 2 slots
    u16 *wh_out = wtsh + SLOT*10, *wl_out = wtsl + SLOT*10;

    // --- dtype probe + normalization ---
    probe_kernel<<<1, 64, 0, stream>>>(ptr_raw, mask_raw, flags);
    conv_int_kernel<<<1, 64, 0, stream>>>(ptr_raw, ptr32, flags, B + 1);
    conv_int_kernel<<<(2*E + 255)/256, 256, 0, stream>>>(ei_raw, ei32, flags, 2*E);
    maskbits_kernel<<<(Mn/64 + 255)/256, 256, 0, stream>>>(mask_raw, mbits, flags, Mn/64);

    // --- CSR inversion ---
    hipMemsetAsync(deg, 0, (size_t)N*sizeof(int), stream);
    hipMemsetAsync(cursor, 0, (size_t)N*sizeof(int), stream);
    count_kernel<<<(E+255)/256, 256, 0, stream>>>(ei32, deg, E, N);
    scan_kernel<<<1, 1024, 0, stream>>>(deg, offs, N);
    fill_kernel<<<(E+255)/256, 256, 0, stream>>>(ei32, offs, cursor, in_src, E, N);

    // --- weight transpose + split convert ---
    transpose_kernel<<<dim3(16,16), 256, 0, stream>>>(v_w, wh_v, wl_v, D, D);
    for (int i = 0; i < NGIN; i++){
        transpose_kernel<<<dim3(16,16), 256, 0, stream>>>(gin_w1 + (size_t)i*D*D, wh_g[2*i],   wl_g[2*i],   D, D);
        transpose_kernel<<<dim3(16,16), 256, 0, stream>>>(gin_w2 + (size_t)i*D*D, wh_g[2*i+1], wl_g[2*i+1], D, D);
    }
    transpose_kernel<<<dim3(16,16), 256, 0, stream>>>(se_w,  wh_se,  wl_se,  D, D);
    transpose_kernel<<<dim3(32,16), 256, 0, stream>>>(qk_w,  wh_qk,  wl_qk,  D, 2*D);
    transpose_kernel<<<dim3(16,16), 256, 0, stream>>>(out_w, wh_out, wl_out, D, D);

    dim3 g512(4, N/128), g1024(8, N/128);

    // v = x @ v_w + v_b
    gemm_mfma<0><<<g512, 256, 0, stream>>>(x, wh_v, wl_v, v_b, vbuf, D, D);

    // GIN layers
    const float* h = x;
    for (int i = 0; i < NGIN; i++){
        gather_kernel<<<N, 256, 0, stream>>>(h, offs, in_src, bufB);
        gemm_mfma<1><<<g512, 256, 0, stream>>>(bufB, wh_g[2*i],   wl_g[2*i],   gin_b1 + (size_t)i*D, bufC, D, D);
        gemm_mfma<1><<<g512, 256, 0, stream>>>(bufC, wh_g[2*i+1], wl_g[2*i+1], gin_b2 + (size_t)i*D, bufA, D, D);
        h = bufA;
    }

    // BatchNorm (batch stats, biased var)
    hipMemsetAsync(sums, 0, 1024*sizeof(float), stream);
    bn_stats_kernel<<<(N+127)/128, 256, 0, stream>>>(bufA, sums, N);
    bn_final_kernel<<<1, 512, 0, stream>>>(sums, bn_gamma, bn_beta, sc, N);
    bn_apply_kernel<<<(N*D/4 + 255)/256, 256, 0, stream>>>(bufA, sc, bufB, N*D/4);

    // x_struct = bn(h) @ se_w + se_b
    gemm_mfma<0><<<g512, 256, 0, stream>>>(bufB, wh_se, wl_se, se_b, bufC, D, D);

    // qk = x_struct @ qk_w + qk_b
    gemm_mfma<0><<<g1024, 256, 0, stream>>>(bufC, wh_qk, wl_qk, qk_b, qkbuf, D, 2*D);

    // attention (MFMA, split-bf16 QK^T) -> bufC
    attn_mfma_kernel<<<dim3(LMAX/64, NHEAD, B), 256, 0, stream>>>(qkbuf, vbuf, mbits, ptr32, bufC, N);

    // out = attn_out @ out_w + out_b
    gemm_mfma<0><<<g512, 256, 0, stream>>>(bufC, wh_out, wl_out, out_b, (float*)d_out, N == 0 ? D : D, D);
}

// Round 8
// 699.768 us; speedup vs baseline: 4.4349x; 1.0247x over previous
//
#include <hip/hip_runtime.h>
#include <hip/hip_bf16.h>
#include <cstdint>
#include <cstddef>

#define D 512
#define NHEAD 8
#define LMAX 512
#define NGIN 3

typedef unsigned short u16;
typedef unsigned long long u64;
typedef __attribute__((ext_vector_type(8))) short short8;
typedef __attribute__((ext_vector_type(8))) unsigned short ushort8;
typedef __attribute__((ext_vector_type(4))) unsigned short us4;
typedef __attribute__((ext_vector_type(4))) float f32x4;

static __device__ inline u16 f2bf(float f){
    union { float f; uint32_t u; } c; c.f = f;
    uint32_t r = (c.u + 0x7fffu + ((c.u >> 16) & 1u)) >> 16;
    return (u16)r;
}
static __device__ inline float bf2f(u16 h){
    union { uint32_t u; float f; } c; c.u = ((uint32_t)h) << 16; return c.f;
}

// ---------------- dtype probe + normalization ----------------
__global__ void probe_kernel(const int* __restrict__ ptr_raw,
                             const unsigned char* __restrict__ mask_raw,
                             int* __restrict__ flags){
    if (threadIdx.x == 0){
        flags[0] = (ptr_raw[1] == 0) ? 1 : 0;
        int cntOdd = 0, cnt4 = 0;
        for (int i = 1; i < 2048; i += 2) cntOdd += (mask_raw[i] != 0);
        for (int i = 4; i < 2048; i += 8) cnt4   += (mask_raw[i] != 0);
        flags[1] = (cntOdd > 64) ? 1 : ((cnt4 > 16) ? 4 : 8);
    }
}

__global__ void conv_int_kernel(const int* __restrict__ raw, int* __restrict__ outp,
                                const int* __restrict__ flags, int n){
    int i = blockIdx.x*256 + threadIdx.x;
    if (i < n) outp[i] = flags[0] ? raw[2*i] : raw[i];
}

// pack DAG mask into bits: maskbits[(b*512 + r)*8 + t] bit j = mask[b][r][t*64+j]
__global__ void maskbits_kernel(const unsigned char* __restrict__ raw,
                                u64* __restrict__ outp,
                                const int* __restrict__ flags, int total){
    int idx = blockIdx.x*256 + threadIdx.x;
    if (idx >= total) return;
    int w = flags[1];
    size_t ebase = (size_t)(idx >> 3) * 512 + (size_t)(idx & 7) * 64;
    u64 bits = 0;
    if (w == 1){
        const u64* p8 = (const u64*)(raw + ebase);
        #pragma unroll
        for (int g = 0; g < 8; g++){
            u64 v = p8[g];
            #pragma unroll
            for (int by = 0; by < 8; by++)
                if ((v >> (by*8)) & 0xffull) bits |= 1ull << (g*8 + by);
        }
    } else {
        for (int j = 0; j < 64; j++)
            if (raw[(ebase + j) * (size_t)w]) bits |= 1ull << j;
    }
    outp[idx] = bits;
}

// ---------------- CSR inversion ----------------
__global__ void count_kernel(const int* __restrict__ ei, int* __restrict__ deg, int E, int N){
    int e = blockIdx.x*256 + threadIdx.x;
    if (e < E){
        int d = ei[E + e];
        if ((unsigned)d < (unsigned)N) atomicAdd(&deg[d], 1);
    }
}

// 1024-thread wave-shuffle scan
__global__ void scan_kernel(const int* __restrict__ deg, int* __restrict__ offs, int n){
    __shared__ int wsum[16];
    __shared__ int carry_s;
    int tid = threadIdx.x, lane = tid & 63, wv = tid >> 6;
    if (tid == 0){ carry_s = 0; offs[0] = 0; }
    __syncthreads();
    int nChunks = (n + 1023) / 1024;
    for (int ch = 0; ch < nChunks; ch++){
        int i = ch*1024 + tid;
        int val = (i < n) ? deg[i] : 0;
        int s = val;
        #pragma unroll
        for (int off = 1; off < 64; off <<= 1){
            int t = __shfl_up(s, off);
            if (lane >= off) s += t;
        }
        if (lane == 63) wsum[wv] = s;
        __syncthreads();
        if (wv == 0){
            int t = (lane < 16) ? wsum[lane] : 0;
            #pragma unroll
            for (int off = 1; off < 16; off <<= 1){
                int u = __shfl_up(t, off);
                if (lane >= off) t += u;
            }
            if (lane < 16) wsum[lane] = t;
        }
        __syncthreads();
        int wbase = wv ? wsum[wv-1] : 0;
        if (i < n) offs[i+1] = carry_s + wbase + s;
        __syncthreads();
        if (tid == 1023) carry_s += wsum[15];
        __syncthreads();
    }
}

__global__ void fill_kernel(const int* __restrict__ ei, const int* __restrict__ offs,
                            int* __restrict__ cursor, int* __restrict__ in_src, int E, int N){
    int e = blockIdx.x*256 + threadIdx.x;
    if (e < E){
        int d = ei[E + e];
        if ((unsigned)d < (unsigned)N){
            int slot = atomicAdd(&cursor[d], 1);
            in_src[offs[d] + slot] = ei[e];
        }
    }
}

// ---------------- split f32 -> hi/lo bf16 planes ----------------
__global__ void split_kernel(const float* __restrict__ in, u16* __restrict__ hi,
                             u16* __restrict__ lo, int total4){
    int i = blockIdx.x*256 + threadIdx.x;
    if (i >= total4) return;
    float4 v = *(const float4*)(in + (size_t)i*4);
    float fv[4] = {v.x, v.y, v.z, v.w};
    us4 h4, l4;
    #pragma unroll
    for (int j = 0; j < 4; j++){
        u16 hh = f2bf(fv[j]);
        h4[j] = hh;
        l4[j] = f2bf(fv[j] - bf2f(hh));
    }
    *(us4*)(hi + (size_t)i*4) = h4;
    *(us4*)(lo + (size_t)i*4) = l4;
}

// ---------------- gather: out = h[n] + sum_{incoming} h[src], split-bf16 out ----------------
template<int INF32>
__global__ __launch_bounds__(256) void gather_kernel(const float* __restrict__ hf,
        const u16* __restrict__ hh, const u16* __restrict__ hl,
        const int* __restrict__ offs, const int* __restrict__ in_src,
        u16* __restrict__ oh, u16* __restrict__ ol){
    int node = blockIdx.x;
    int tid = threadIdx.x;
    float a0, a1;
    size_t rb = (size_t)node*D;
    if (INF32){ a0 = hf[rb + tid]; a1 = hf[rb + tid + 256]; }
    else {
        a0 = bf2f(hh[rb + tid])       + bf2f(hl[rb + tid]);
        a1 = bf2f(hh[rb + tid + 256]) + bf2f(hl[rb + tid + 256]);
    }
    int s = offs[node], e = offs[node+1];
    for (int i = s; i < e; i++){
        size_t sb = (size_t)in_src[i]*D;
        if (INF32){ a0 += hf[sb + tid]; a1 += hf[sb + tid + 256]; }
        else {
            a0 += bf2f(hh[sb + tid])       + bf2f(hl[sb + tid]);
            a1 += bf2f(hh[sb + tid + 256]) + bf2f(hl[sb + tid + 256]);
        }
    }
    u16 h0 = f2bf(a0), h1 = f2bf(a1);
    oh[rb + tid] = h0;        ol[rb + tid] = f2bf(a0 - bf2f(h0));
    oh[rb + tid + 256] = h1;  ol[rb + tid + 256] = f2bf(a1 - bf2f(h1));
}

// ---------------- weight transpose + split-bf16 convert ----------------
__global__ __launch_bounds__(256) void transpose_kernel(const float* __restrict__ W,
        u16* __restrict__ Wh, u16* __restrict__ Wl, int K, int Nout){
    __shared__ float T[32][33];
    int nb = blockIdx.x*32, kb = blockIdx.y*32;
    int ln = threadIdx.x & 31, lk = threadIdx.x >> 5;
    #pragma unroll
    for (int i = 0; i < 4; i++)
        T[lk + 8*i][ln] = W[(size_t)(kb + lk + 8*i)*Nout + nb + ln];
    __syncthreads();
    #pragma unroll
    for (int i = 0; i < 4; i++){
        float val = T[ln][lk + 8*i];
        u16 h = f2bf(val);
        size_t idx = (size_t)(nb + lk + 8*i)*K + kb + ln;
        Wh[idx] = h;
        Wl[idx] = f2bf(val - bf2f(h));
    }
}

// ---------------- split-bf16 MFMA GEMM, pre-split A ----------------
// A = hi/lo planes [M][K] bf16. Wt = hi/lo [Nout][K]. 3-term split product.
// EPI: 0 = f32 out (C0), 1 = split out (C0 hi, C1 lo), 2 = plain bf16 out (C0).
#define GS 72
template<int ACT, int EPI>
__global__ __launch_bounds__(256) void gemm_ps(const u16* __restrict__ Ahg,
        const u16* __restrict__ Alg,
        const u16* __restrict__ Wth, const u16* __restrict__ Wtl,
        const float* __restrict__ bias,
        void* __restrict__ C0, void* __restrict__ C1, int K, int Nout){
    __shared__ u16 Ah[128][GS];
    __shared__ u16 Al[128][GS];
    __shared__ u16 Bh[128][GS];
    __shared__ u16 Bl[128][GS];
    int tid = threadIdx.x;
    int rowBase = blockIdx.y*128, colBase = blockIdx.x*128;
    int w = tid >> 6, l = tid & 63, lg = l >> 4, lm = l & 15;
    int wr = w >> 1, wc = w & 1;
    f32x4 acc[4][4] = {};
    int sr = tid >> 1, skb = (tid & 1)*32;
    const u16* Ahp = Ahg + (size_t)(rowBase + sr)*K + skb;
    const u16* Alp = Alg + (size_t)(rowBase + sr)*K + skb;
    const u16* Wph = Wth + (size_t)(colBase + sr)*K + skb;
    const u16* Wpl = Wtl + (size_t)(colBase + sr)*K + skb;
    for (int k0 = 0; k0 < K; k0 += 64){
        #pragma unroll
        for (int i = 0; i < 4; i++){
            *(ushort8*)&Ah[sr][skb + i*8] = *(const ushort8*)(Ahp + k0 + i*8);
            *(ushort8*)&Al[sr][skb + i*8] = *(const ushort8*)(Alp + k0 + i*8);
            *(ushort8*)&Bh[sr][skb + i*8] = *(const ushort8*)(Wph + k0 + i*8);
            *(ushort8*)&Bl[sr][skb + i*8] = *(const ushort8*)(Wpl + k0 + i*8);
        }
        __syncthreads();
        #pragma unroll
        for (int ks = 0; ks < 2; ks++){
            short8 ah[4], al[4], bh[4], bl[4];
            #pragma unroll
            for (int mf = 0; mf < 4; mf++){
                ah[mf] = *(const short8*)&Ah[wr*64 + mf*16 + lm][ks*32 + lg*8];
                al[mf] = *(const short8*)&Al[wr*64 + mf*16 + lm][ks*32 + lg*8];
            }
            #pragma unroll
            for (int nf = 0; nf < 4; nf++){
                bh[nf] = *(const short8*)&Bh[wc*64 + nf*16 + lm][ks*32 + lg*8];
                bl[nf] = *(const short8*)&Bl[wc*64 + nf*16 + lm][ks*32 + lg*8];
            }
            #pragma unroll
            for (int mf = 0; mf < 4; mf++)
                #pragma unroll
                for (int nf = 0; nf < 4; nf++){
                    acc[mf][nf] = __builtin_amdgcn_mfma_f32_16x16x32_bf16(ah[mf], bh[nf], acc[mf][nf], 0, 0, 0);
                    acc[mf][nf] = __builtin_amdgcn_mfma_f32_16x16x32_bf16(al[mf], bh[nf], acc[mf][nf], 0, 0, 0);
                    acc[mf][nf] = __builtin_amdgcn_mfma_f32_16x16x32_bf16(ah[mf], bl[nf], acc[mf][nf], 0, 0, 0);
                }
        }
        __syncthreads();
    }
    #pragma unroll
    for (int nf = 0; nf < 4; nf++){
        int col = colBase + wc*64 + nf*16 + lm;
        float bv = bias[col];
        #pragma unroll
        for (int mf = 0; mf < 4; mf++){
            int row = rowBase + wr*64 + mf*16 + lg*4;
            #pragma unroll
            for (int j = 0; j < 4; j++){
                float o = acc[mf][nf][j] + bv;
                if (ACT) o = fmaxf(o, 0.f);
                size_t idx = (size_t)(row + j)*Nout + col;
                if (EPI == 0){
                    ((float*)C0)[idx] = o;
                } else if (EPI == 1){
                    u16 hh = f2bf(o);
                    ((u16*)C0)[idx] = hh;
                    ((u16*)C1)[idx] = f2bf(o - bf2f(hh));
                } else {
                    ((u16*)C0)[idx] = f2bf(o);
                }
            }
        }
    }
}

// ---------------- BatchNorm (split in / split out) ----------------
__global__ __launch_bounds__(256) void bn_stats_kernel(const u16* __restrict__ Ah,
        const u16* __restrict__ Al, float* __restrict__ sums, int n){
    int c = threadIdx.x;
    int r0 = blockIdx.x*128, r1 = min(n, r0+128);
    float s0=0.f, s1=0.f, q0=0.f, q1=0.f;
    for (int r = r0; r < r1; r++){
        float v0 = bf2f(Ah[(size_t)r*D + c])       + bf2f(Al[(size_t)r*D + c]);
        float v1 = bf2f(Ah[(size_t)r*D + 256 + c]) + bf2f(Al[(size_t)r*D + 256 + c]);
        s0 += v0; q0 += v0*v0; s1 += v1; q1 += v1*v1;
    }
    atomicAdd(&sums[c], s0);
    atomicAdd(&sums[c+256], s1);
    atomicAdd(&sums[512+c], q0);
    atomicAdd(&sums[512+c+256], q1);
}

__global__ void bn_final_kernel(const float* __restrict__ sums, const float* __restrict__ gamma,
        const float* __restrict__ beta, float* __restrict__ sc, int n){
    int c = threadIdx.x;
    float mean = sums[c] / (float)n;
    float var = sums[512+c] / (float)n - mean*mean;
    float r = rsqrtf(var + 1e-5f);
    float scale = r * gamma[c];
    sc[c] = scale;
    sc[512+c] = beta[c] - mean*scale;
}

__global__ void bn_apply_kernel(const u16* __restrict__ inh, const u16* __restrict__ inl,
        const float* __restrict__ sc, u16* __restrict__ oh, u16* __restrict__ ol, int total4){
    int i = blockIdx.x*256 + threadIdx.x;
    if (i >= total4) return;
    int c4 = (i*4) & (D-1);
    us4 vh = *(const us4*)(inh + (size_t)i*4);
    us4 vl = *(const us4*)(inl + (size_t)i*4);
    float4 s  = *(const float4*)(sc + c4);
    float4 sh = *(const float4*)(sc + 512 + c4);
    float sa[4] = {s.x, s.y, s.z, s.w};
    float ba[4] = {sh.x, sh.y, sh.z, sh.w};
    us4 h4, l4;
    #pragma unroll
    for (int j = 0; j < 4; j++){
        float v = bf2f(vh[j]) + bf2f(vl[j]);
        float o = v*sa[j] + ba[j];
        u16 hh = f2bf(o);
        h4[j] = hh;
        l4[j] = f2bf(o - bf2f(hh));
    }
    *(us4*)(oh + (size_t)i*4) = h4;
    *(us4*)(ol + (size_t)i*4) = l4;
}

// ---------------- MFMA ragged masked flash attention, pre-split inputs ----------------
// qkH/qkL: bf16 planes [N][1024] (K cols 0..511, Q cols 512..1023); vbf: bf16 [N][512].
// Output: split bf16 planes oh/ol [N][512].
#define ATS 72
__global__ __launch_bounds__(256) void attn_mfma_kernel(const u16* __restrict__ qkH,
        const u16* __restrict__ qkL, const u16* __restrict__ vbf,
        const u64* __restrict__ maskbits,
        const int* __restrict__ ptr, u16* __restrict__ oh, u16* __restrict__ ol, int N){
    __shared__ u16 Kh[64][ATS];       // [key][d] hi
    __shared__ u16 Kl[64][ATS];       // [key][d] lo
    __shared__ u16 Vt[64][ATS];       // [d][key]
    __shared__ u16 Pl[4][16][ATS];    // per-wave P [qrow][key]
    int b = blockIdx.z, h = blockIdx.y;
    int base = ptr[b], size = ptr[b+1] - base;
    int q0 = blockIdx.x * 64;
    if (q0 >= size) return;
    int tid = threadIdx.x, w = tid >> 6, l = tid & 63;
    int lg = l >> 4, lm = l & 15;
    short8 qh[2], ql[2];
    {
        int qrow = q0 + w*16 + lm;
        int qr = (qrow < size) ? qrow : 0;
        const u16* qph = qkH + (size_t)(base + qr)*1024 + 512 + h*64;
        const u16* qpl = qkL + (size_t)(base + qr)*1024 + 512 + h*64;
        #pragma unroll
        for (int ks = 0; ks < 2; ks++){
            short8 th = *(const short8*)(qph + ks*32 + lg*8);
            short8 tl = *(const short8*)(qpl + ks*32 + lg*8);
            if (qrow >= size){ th = short8{0,0,0,0,0,0,0,0}; tl = short8{0,0,0,0,0,0,0,0}; }
            qh[ks] = th; ql[ks] = tl;
        }
    }
    f32x4 acco[4] = {};
    float mrow[4], lrow[4];
    #pragma unroll
    for (int j = 0; j < 4; j++){ mrow[j] = -INFINITY; lrow[j] = 0.f; }
    int nt = (size + 63) >> 6;
    for (int t = 0; t < nt; t++){
        int j0 = t*64;
        __syncthreads();
        {   // stage K hi/lo (copies) and V (transposed scatter); wave w covers d-range w*16..+15
            int jj = tid & 63, db = (tid >> 6)*16;
            int key = j0 + jj;
            bool ok = key < size;
            size_t node = (size_t)(base + (ok ? key : 0));
            const u16* khp = qkH + node*1024 + h*64 + db;
            const u16* klp = qkL + node*1024 + h*64 + db;
            const u16* vp  = vbf + node*512  + h*64 + db;
            ushort8 z = {0,0,0,0,0,0,0,0};
            ushort8 kh0 = ok ? *(const ushort8*)(khp)     : z;
            ushort8 kh1 = ok ? *(const ushort8*)(khp + 8) : z;
            ushort8 kl0 = ok ? *(const ushort8*)(klp)     : z;
            ushort8 kl1 = ok ? *(const ushort8*)(klp + 8) : z;
            ushort8 v0  = ok ? *(const ushort8*)(vp)      : z;
            ushort8 v1  = ok ? *(const ushort8*)(vp + 8)  : z;
            *(ushort8*)&Kh[jj][db]     = kh0;
            *(ushort8*)&Kh[jj][db + 8] = kh1;
            *(ushort8*)&Kl[jj][db]     = kl0;
            *(ushort8*)&Kl[jj][db + 8] = kl1;
            #pragma unroll
            for (int i = 0; i < 8; i++){
                Vt[db + i][jj]     = v0[i];
                Vt[db + 8 + i][jj] = v1[i];
            }
        }
        __syncthreads();
        // QK^T (3-term split) -> sc: rows = q (lg*4+j), cols = keys (nf*16+lm)
        f32x4 sc[4] = {};
        #pragma unroll
        for (int nf = 0; nf < 4; nf++)
            #pragma unroll
            for (int ks = 0; ks < 2; ks++){
                short8 kh = *(const short8*)&Kh[nf*16 + lm][ks*32 + lg*8];
                short8 kl = *(const short8*)&Kl[nf*16 + lm][ks*32 + lg*8];
                sc[nf] = __builtin_amdgcn_mfma_f32_16x16x32_bf16(qh[ks], kh, sc[nf], 0, 0, 0);
                sc[nf] = __builtin_amdgcn_mfma_f32_16x16x32_bf16(ql[ks], kh, sc[nf], 0, 0, 0);
                sc[nf] = __builtin_amdgcn_mfma_f32_16x16x32_bf16(qh[ks], kl, sc[nf], 0, 0, 0);
            }
        // mask + online softmax
        u64 mb[4];
        #pragma unroll
        for (int j = 0; j < 4; j++)
            mb[j] = maskbits[((size_t)b*LMAX + (q0 + w*16 + lg*4 + j))*8 + t];
        float mx[4], alpha[4];
        #pragma unroll
        for (int j = 0; j < 4; j++){
            float s0 = -INFINITY;
            #pragma unroll
            for (int nf = 0; nf < 4; nf++){
                int key = j0 + nf*16 + lm;
                float s = sc[nf][j] * 0.125f;
                bool msk = (key >= size) || ((mb[j] >> (nf*16 + lm)) & 1);
                s = msk ? -INFINITY : s;
                sc[nf][j] = s;
                s0 = fmaxf(s0, s);
            }
            #pragma unroll
            for (int off = 1; off < 16; off <<= 1) s0 = fmaxf(s0, __shfl_xor(s0, off));
            mx[j] = s0;
        }
        #pragma unroll
        for (int j = 0; j < 4; j++){
            if (mx[j] == -INFINITY){ alpha[j] = 1.f; }
            else {
                float mn = fmaxf(mrow[j], mx[j]);
                alpha[j] = __expf(mrow[j] - mn);
                mrow[j] = mn;
            }
        }
        float ps[4] = {0.f, 0.f, 0.f, 0.f};
        #pragma unroll
        for (int nf = 0; nf < 4; nf++)
            #pragma unroll
            for (int j = 0; j < 4; j++){
                float p = (mx[j] == -INFINITY) ? 0.f : __expf(sc[nf][j] - mrow[j]);
                ps[j] += p;
                Pl[w][lg*4 + j][nf*16 + lm] = f2bf(p);
            }
        #pragma unroll
        for (int j = 0; j < 4; j++){
            float s = ps[j];
            #pragma unroll
            for (int off = 1; off < 16; off <<= 1) s += __shfl_xor(s, off);
            lrow[j] = lrow[j]*alpha[j] + s;
        }
        #pragma unroll
        for (int df = 0; df < 4; df++)
            #pragma unroll
            for (int j = 0; j < 4; j++) acco[df][j] *= alpha[j];
        #pragma unroll
        for (int ks = 0; ks < 2; ks++){
            short8 pf = *(const short8*)&Pl[w][lm][ks*32 + lg*8];
            #pragma unroll
            for (int df = 0; df < 4; df++){
                short8 vf = *(const short8*)&Vt[df*16 + lm][ks*32 + lg*8];
                acco[df] = __builtin_amdgcn_mfma_f32_16x16x32_bf16(pf, vf, acco[df], 0, 0, 0);
            }
        }
    }
    #pragma unroll
    for (int j = 0; j < 4; j++){
        int r = q0 + w*16 + lg*4 + j;
        if (r < size){
            float inv = 1.f / lrow[j];
            #pragma unroll
            for (int df = 0; df < 4; df++){
                float o = acco[df][j] * inv;
                size_t idx = (size_t)(base + r)*D + h*64 + df*16 + lm;
                u16 hh = f2bf(o);
                oh[idx] = hh;
                ol[idx] = f2bf(o - bf2f(hh));
            }
        }
    }
}

extern "C" void kernel_launch(void* const* d_in, const int* in_sizes, int n_in,
                              void* d_out, int out_size, void* d_ws, size_t ws_size,
                              hipStream_t stream){
    const float* x        = (const float*)d_in[0];
    const int*   ei_raw   = (const int*)d_in[1];
    const unsigned char* mask_raw = (const unsigned char*)d_in[2];
    const int*   ptr_raw  = (const int*)d_in[3];
    const float* gin_w1   = (const float*)d_in[4];
    const float* gin_b1   = (const float*)d_in[5];
    const float* gin_w2   = (const float*)d_in[6];
    const float* gin_b2   = (const float*)d_in[7];
    const float* bn_gamma = (const float*)d_in[8];
    const float* bn_beta  = (const float*)d_in[9];
    const float* se_w     = (const float*)d_in[10];
    const float* se_b     = (const float*)d_in[11];
    const float* qk_w     = (const float*)d_in[12];
    const float* qk_b     = (const float*)d_in[13];
    const float* v_w      = (const float*)d_in[14];
    const float* v_b      = (const float*)d_in[15];
    const float* out_w    = (const float*)d_in[16];
    const float* out_b    = (const float*)d_in[17];

    const int N  = in_sizes[0] / D;       // 12160
    const int E  = in_sizes[1] / 2;       // 97280
    const int B  = in_sizes[3] - 1;       // 32
    const int Mn = in_sizes[2];           // B*512*512

    char* ws = (char*)d_ws;
    char* p = ws;
    auto alloc = [&](size_t bytes) -> char* {
        char* q = p; p += (bytes + 255) & ~(size_t)255; return q;
    };
    size_t PLANE = (size_t)N * D * sizeof(u16);        // 12.45 MB
    // activation pairs: [hi plane][lo plane] contiguous (pair base doubles as an N x 1024 plane)
    u16* pairX = (u16*)alloc(2*PLANE);
    u16* pairG = (u16*)alloc(2*PLANE);
    u16* pairT = (u16*)alloc(2*PLANE);
    u16* pairH = (u16*)alloc(2*PLANE);
    u16* v_bf  = (u16*)alloc(PLANE);
    u16* Xh = pairX, *Xl = pairX + (size_t)N*D;
    u16* Gh = pairG, *Gl = pairG + (size_t)N*D;
    u16* Th = pairT, *Tl = pairT + (size_t)N*D;
    u16* Hh = pairH, *Hl = pairH + (size_t)N*D;
    float* sums   = (float*)alloc(1024*sizeof(float));
    float* sc     = (float*)alloc(1024*sizeof(float));
    int*   flags  = (int*)alloc(16*sizeof(int));
    int*   deg    = (int*)alloc((size_t)N*sizeof(int));
    int*   offs   = (int*)alloc((size_t)(N+1)*sizeof(int));
    int*   cursor = (int*)alloc((size_t)N*sizeof(int));
    int*   in_src = (int*)alloc((size_t)E*sizeof(int));
    int*   ptr32  = (int*)alloc(64*sizeof(int));
    int*   ei32   = (int*)alloc((size_t)2*E*sizeof(int));
    u64*   mbits  = (u64*)alloc((size_t)(Mn/64)*sizeof(u64));
    u16*   wtsh   = (u16*)alloc((size_t)2883584*sizeof(u16));
    u16*   wtsl   = (u16*)alloc((size_t)2883584*sizeof(u16));
    const size_t SLOT = 262144;
    u16 *wh_v = wtsh, *wl_v = wtsl;
    u16 *wh_g[6], *wl_g[6];
    for (int i = 0; i < 6; i++){ wh_g[i] = wtsh + SLOT*(1+i); wl_g[i] = wtsl + SLOT*(1+i); }
    u16 *wh_se  = wtsh + SLOT*7,  *wl_se  = wtsl + SLOT*7;
    u16 *wh_qk  = wtsh + SLOT*8,  *wl_qk  = wtsl + SLOT*8;
    u16 *wh_out = wtsh + SLOT*10, *wl_out = wtsl + SLOT*10;

    // --- dtype probe + normalization ---
    probe_kernel<<<1, 64, 0, stream>>>(ptr_raw, mask_raw, flags);
    conv_int_kernel<<<1, 64, 0, stream>>>(ptr_raw, ptr32, flags, B + 1);
    conv_int_kernel<<<(2*E + 255)/256, 256, 0, stream>>>(ei_raw, ei32, flags, 2*E);
    maskbits_kernel<<<(Mn/64 + 255)/256, 256, 0, stream>>>(mask_raw, mbits, flags, Mn/64);

    // --- CSR inversion ---
    hipMemsetAsync(deg, 0, (size_t)N*sizeof(int), stream);
    hipMemsetAsync(cursor, 0, (size_t)N*sizeof(int), stream);
    count_kernel<<<(E+255)/256, 256, 0, stream>>>(ei32, deg, E, N);
    scan_kernel<<<1, 1024, 0, stream>>>(deg, offs, N);
    fill_kernel<<<(E+255)/256, 256, 0, stream>>>(ei32, offs, cursor, in_src, E, N);

    // --- weight transpose + split convert ---
    transpose_kernel<<<dim3(16,16), 256, 0, stream>>>(v_w, wh_v, wl_v, D, D);
    for (int i = 0; i < NGIN; i++){
        transpose_kernel<<<dim3(16,16), 256, 0, stream>>>(gin_w1 + (size_t)i*D*D, wh_g[2*i],   wl_g[2*i],   D, D);
        transpose_kernel<<<dim3(16,16), 256, 0, stream>>>(gin_w2 + (size_t)i*D*D, wh_g[2*i+1], wl_g[2*i+1], D, D);
    }
    transpose_kernel<<<dim3(16,16), 256, 0, stream>>>(se_w,  wh_se,  wl_se,  D, D);
    transpose_kernel<<<dim3(32,16), 256, 0, stream>>>(qk_w,  wh_qk,  wl_qk,  D, 2*D);
    transpose_kernel<<<dim3(16,16), 256, 0, stream>>>(out_w, wh_out, wl_out, D, D);

    // x -> split pair X (for v GEMM)
    split_kernel<<<(N*D/4 + 255)/256, 256, 0, stream>>>(x, Xh, Xl, N*D/4);

    dim3 g512(4, N/128), g1024(8, N/128);

    // v = x @ v_w + v_b  -> plain bf16
    gemm_ps<0,2><<<g512, 256, 0, stream>>>(Xh, Xl, wh_v, wl_v, v_b, v_bf, nullptr, D, D);

    // GIN layers (split activations throughout)
    for (int i = 0; i < NGIN; i++){
        if (i == 0)
            gather_kernel<1><<<N, 256, 0, stream>>>(x, nullptr, nullptr, offs, in_src, Gh, Gl);
        else
            gather_kernel<0><<<N, 256, 0, stream>>>(nullptr, Hh, Hl, offs, in_src, Gh, Gl);
        gemm_ps<1,1><<<g512, 256, 0, stream>>>(Gh, Gl, wh_g[2*i],   wl_g[2*i],   gin_b1 + (size_t)i*D, Th, Tl, D, D);
        gemm_ps<1,1><<<g512, 256, 0, stream>>>(Th, Tl, wh_g[2*i+1], wl_g[2*i+1], gin_b2 + (size_t)i*D, Hh, Hl, D, D);
    }

    // BatchNorm (batch stats, biased var): pairH -> pairG
    hipMemsetAsync(sums, 0, 1024*sizeof(float), stream);
    bn_stats_kernel<<<(N+127)/128, 256, 0, stream>>>(Hh, Hl, sums, N);
    bn_final_kernel<<<1, 512, 0, stream>>>(sums, bn_gamma, bn_beta, sc, N);
    bn_apply_kernel<<<(N*D/4 + 255)/256, 256, 0, stream>>>(Hh, Hl, sc, Gh, Gl, N*D/4);

    // x_struct = bn @ se_w + se_b : pairG -> pairT (split)
    gemm_ps<0,1><<<g512, 256, 0, stream>>>(Gh, Gl, wh_se, wl_se, se_b, Th, Tl, D, D);

    // qk = x_struct @ qk_w + qk_b : pairT -> hi plane = pairX (N x 1024), lo plane = pairG
    gemm_ps<0,1><<<g1024, 256, 0, stream>>>(Th, Tl, wh_qk, wl_qk, qk_b, pairX, pairG, D, 2*D);

    // attention: split qk + bf16 v -> split output in pairT
    attn_mfma_kernel<<<dim3(LMAX/64, NHEAD, B), 256, 0, stream>>>(pairX, pairG, v_bf, mbits, ptr32, Th, Tl, N);

    // out = attn_out @ out_w + out_b -> f32 d_out
    gemm_ps<0,0><<<g512, 256, 0, stream>>>(Th, Tl, wh_out, wl_out, out_b, (float*)d_out, nullptr, D, D);
}

// Round 9
// 646.392 us; speedup vs baseline: 4.8012x; 1.0826x over previous
//
#include <hip/hip_runtime.h>
#include <hip/hip_bf16.h>
#include <cstdint>
#include <cstddef>

#define D 512
#define NHEAD 8
#define LMAX 512
#define NGIN 3

typedef unsigned short u16;
typedef unsigned long long u64;
typedef __attribute__((ext_vector_type(8))) short short8;
typedef __attribute__((ext_vector_type(8))) unsigned short ushort8;
typedef __attribute__((ext_vector_type(4))) unsigned short us4;
typedef __attribute__((ext_vector_type(4))) float f32x4;

static __device__ inline u16 f2bf(float f){
    union { float f; uint32_t u; } c; c.f = f;
    uint32_t r = (c.u + 0x7fffu + ((c.u >> 16) & 1u)) >> 16;
    return (u16)r;
}
static __device__ inline float bf2f(u16 h){
    union { uint32_t u; float f; } c; c.u = ((uint32_t)h) << 16; return c.f;
}

#define GLOAD_LDS16(SRC, DST) \
    __builtin_amdgcn_global_load_lds( \
        (const __attribute__((address_space(1))) void*)(SRC), \
        (__attribute__((address_space(3))) void*)(DST), 16, 0, 0)

// ---------------- dtype probe + normalization ----------------
__global__ void probe_kernel(const int* __restrict__ ptr_raw,
                             const unsigned char* __restrict__ mask_raw,
                             int* __restrict__ flags){
    if (threadIdx.x == 0){
        flags[0] = (ptr_raw[1] == 0) ? 1 : 0;
        int cntOdd = 0, cnt4 = 0;
        for (int i = 1; i < 2048; i += 2) cntOdd += (mask_raw[i] != 0);
        for (int i = 4; i < 2048; i += 8) cnt4   += (mask_raw[i] != 0);
        flags[1] = (cntOdd > 64) ? 1 : ((cnt4 > 16) ? 4 : 8);
    }
}

__global__ void conv_int_kernel(const int* __restrict__ raw, int* __restrict__ outp,
                                const int* __restrict__ flags, int n){
    int i = blockIdx.x*256 + threadIdx.x;
    if (i < n) outp[i] = flags[0] ? raw[2*i] : raw[i];
}

// pack DAG mask into bits
__global__ void maskbits_kernel(const unsigned char* __restrict__ raw,
                                u64* __restrict__ outp,
                                const int* __restrict__ flags, int total){
    int idx = blockIdx.x*256 + threadIdx.x;
    if (idx >= total) return;
    int w = flags[1];
    size_t ebase = (size_t)(idx >> 3) * 512 + (size_t)(idx & 7) * 64;
    u64 bits = 0;
    if (w == 1){
        const u64* p8 = (const u64*)(raw + ebase);
        #pragma unroll
        for (int g = 0; g < 8; g++){
            u64 v = p8[g];
            #pragma unroll
            for (int by = 0; by < 8; by++)
                if ((v >> (by*8)) & 0xffull) bits |= 1ull << (g*8 + by);
        }
    } else {
        for (int j = 0; j < 64; j++)
            if (raw[(ebase + j) * (size_t)w]) bits |= 1ull << j;
    }
    outp[idx] = bits;
}

// ---------------- CSR inversion ----------------
__global__ void count_kernel(const int* __restrict__ ei, int* __restrict__ deg, int E, int N){
    int e = blockIdx.x*256 + threadIdx.x;
    if (e < E){
        int d = ei[E + e];
        if ((unsigned)d < (unsigned)N) atomicAdd(&deg[d], 1);
    }
}

__global__ void scan_kernel(const int* __restrict__ deg, int* __restrict__ offs, int n){
    __shared__ int wsum[16];
    __shared__ int carry_s;
    int tid = threadIdx.x, lane = tid & 63, wv = tid >> 6;
    if (tid == 0){ carry_s = 0; offs[0] = 0; }
    __syncthreads();
    int nChunks = (n + 1023) / 1024;
    for (int ch = 0; ch < nChunks; ch++){
        int i = ch*1024 + tid;
        int val = (i < n) ? deg[i] : 0;
        int s = val;
        #pragma unroll
        for (int off = 1; off < 64; off <<= 1){
            int t = __shfl_up(s, off);
            if (lane >= off) s += t;
        }
        if (lane == 63) wsum[wv] = s;
        __syncthreads();
        if (wv == 0){
            int t = (lane < 16) ? wsum[lane] : 0;
            #pragma unroll
            for (int off = 1; off < 16; off <<= 1){
                int u = __shfl_up(t, off);
                if (lane >= off) t += u;
            }
            if (lane < 16) wsum[lane] = t;
        }
        __syncthreads();
        int wbase = wv ? wsum[wv-1] : 0;
        if (i < n) offs[i+1] = carry_s + wbase + s;
        __syncthreads();
        if (tid == 1023) carry_s += wsum[15];
        __syncthreads();
    }
}

__global__ void fill_kernel(const int* __restrict__ ei, const int* __restrict__ offs,
                            int* __restrict__ cursor, int* __restrict__ in_src, int E, int N){
    int e = blockIdx.x*256 + threadIdx.x;
    if (e < E){
        int d = ei[E + e];
        if ((unsigned)d < (unsigned)N){
            int slot = atomicAdd(&cursor[d], 1);
            in_src[offs[d] + slot] = ei[e];
        }
    }
}

// ---------------- split f32 -> hi/lo bf16 planes ----------------
__global__ void split_kernel(const float* __restrict__ in, u16* __restrict__ hi,
                             u16* __restrict__ lo, int total4){
    int i = blockIdx.x*256 + threadIdx.x;
    if (i >= total4) return;
    float4 v = *(const float4*)(in + (size_t)i*4);
    float fv[4] = {v.x, v.y, v.z, v.w};
    us4 h4, l4;
    #pragma unroll
    for (int j = 0; j < 4; j++){
        u16 hh = f2bf(fv[j]);
        h4[j] = hh;
        l4[j] = f2bf(fv[j] - bf2f(hh));
    }
    *(us4*)(hi + (size_t)i*4) = h4;
    *(us4*)(lo + (size_t)i*4) = l4;
}

// ---------------- gather (split in/out, us4 vectorized, 2 nodes/block) ----------------
__global__ __launch_bounds__(256) void gather_kernel(const u16* __restrict__ hh,
        const u16* __restrict__ hl,
        const int* __restrict__ offs, const int* __restrict__ in_src,
        u16* __restrict__ oh, u16* __restrict__ ol, int N){
    int node = blockIdx.x*2 + (threadIdx.x >> 7);
    if (node >= N) return;
    int t = threadIdx.x & 127;
    size_t rb = (size_t)node*D + t*4;
    us4 vh = *(const us4*)(hh + rb);
    us4 vl = *(const us4*)(hl + rb);
    float a[4];
    #pragma unroll
    for (int j = 0; j < 4; j++) a[j] = bf2f(vh[j]) + bf2f(vl[j]);
    int s = offs[node], e = offs[node+1];
    for (int i = s; i < e; i++){
        size_t sb = (size_t)in_src[i]*D + t*4;
        us4 nh = *(const us4*)(hh + sb);
        us4 nl = *(const us4*)(hl + sb);
        #pragma unroll
        for (int j = 0; j < 4; j++) a[j] += bf2f(nh[j]) + bf2f(nl[j]);
    }
    us4 h4, l4;
    #pragma unroll
    for (int j = 0; j < 4; j++){
        u16 hh2 = f2bf(a[j]);
        h4[j] = hh2;
        l4[j] = f2bf(a[j] - bf2f(hh2));
    }
    *(us4*)(oh + rb) = h4;
    *(us4*)(ol + rb) = l4;
}

// ---------------- weight transpose + split-bf16 convert ----------------
__global__ __launch_bounds__(256) void transpose_kernel(const float* __restrict__ W,
        u16* __restrict__ Wh, u16* __restrict__ Wl, int K, int Nout){
    __shared__ float T[32][33];
    int nb = blockIdx.x*32, kb = blockIdx.y*32;
    int ln = threadIdx.x & 31, lk = threadIdx.x >> 5;
    #pragma unroll
    for (int i = 0; i < 4; i++)
        T[lk + 8*i][ln] = W[(size_t)(kb + lk + 8*i)*Nout + nb + ln];
    __syncthreads();
    #pragma unroll
    for (int i = 0; i < 4; i++){
        float val = T[ln][lk + 8*i];
        u16 h = f2bf(val);
        size_t idx = (size_t)(nb + lk + 8*i)*K + kb + ln;
        Wh[idx] = h;
        Wl[idx] = f2bf(val - bf2f(h));
    }
}

// ---------------- split-bf16 MFMA GEMM, global_load_lds + XOR-swizzle ----------------
// LDS planes linear [128][64]; LDS[row][cg] = G[row][cg ^ (row&7)] (16B col-groups).
// EPI: 0 = f32 out, 1 = split out (C0 hi, C1 lo), 2 = plain bf16 out.
template<int ACT, int EPI>
__global__ __launch_bounds__(256) void gemm_ps(const u16* __restrict__ Ahg,
        const u16* __restrict__ Alg,
        const u16* __restrict__ Wth, const u16* __restrict__ Wtl,
        const float* __restrict__ bias,
        void* __restrict__ C0, void* __restrict__ C1, int K, int Nout){
    __shared__ __align__(16) u16 Ah[128][64];
    __shared__ __align__(16) u16 Al[128][64];
    __shared__ __align__(16) u16 Bh[128][64];
    __shared__ __align__(16) u16 Bl[128][64];
    int tid = threadIdx.x;
    int rowBase = blockIdx.y*128, colBase = blockIdx.x*128;
    int w = tid >> 6, l = tid & 63, lg = l >> 4, lm = l & 15;
    int wr = w >> 1, wc = w & 1;
    f32x4 acc[4][4] = {};
    const u16* Ahp = Ahg + (size_t)rowBase*K;
    const u16* Alp = Alg + (size_t)rowBase*K;
    const u16* Wph = Wth + (size_t)colBase*K;
    const u16* Wpl = Wtl + (size_t)colBase*K;
    // per-call source indices: slot = c*256 + tid; row = slot>>3; cg = slot&7; scg = cg^(row&7)
    int srow[4], scol[4];
    #pragma unroll
    for (int c = 0; c < 4; c++){
        int slot = c*256 + tid;
        srow[c] = slot >> 3;
        scol[c] = ((slot & 7) ^ (srow[c] & 7)) * 8;
    }
    for (int k0 = 0; k0 < K; k0 += 64){
        #pragma unroll
        for (int c = 0; c < 4; c++){
            int slot = c*256 + tid;
            size_t so = (size_t)srow[c]*K + k0 + scol[c];
            GLOAD_LDS16(Ahp + so, &Ah[0][0] + slot*8);
            GLOAD_LDS16(Alp + so, &Al[0][0] + slot*8);
            GLOAD_LDS16(Wph + so, &Bh[0][0] + slot*8);
            GLOAD_LDS16(Wpl + so, &Bl[0][0] + slot*8);
        }
        __syncthreads();
        #pragma unroll
        for (int ks = 0; ks < 2; ks++){
            int scg = ((ks*4 + lg) ^ (lm & 7)) * 8;   // swizzled read col (u16 units)
            short8 ah[4], al[4], bh[4], bl[4];
            #pragma unroll
            for (int mf = 0; mf < 4; mf++){
                ah[mf] = *(const short8*)&Ah[wr*64 + mf*16 + lm][scg];
                al[mf] = *(const short8*)&Al[wr*64 + mf*16 + lm][scg];
            }
            #pragma unroll
            for (int nf = 0; nf < 4; nf++){
                bh[nf] = *(const short8*)&Bh[wc*64 + nf*16 + lm][scg];
                bl[nf] = *(const short8*)&Bl[wc*64 + nf*16 + lm][scg];
            }
            #pragma unroll
            for (int mf = 0; mf < 4; mf++)
                #pragma unroll
                for (int nf = 0; nf < 4; nf++){
                    acc[mf][nf] = __builtin_amdgcn_mfma_f32_16x16x32_bf16(ah[mf], bh[nf], acc[mf][nf], 0, 0, 0);
                    acc[mf][nf] = __builtin_amdgcn_mfma_f32_16x16x32_bf16(al[mf], bh[nf], acc[mf][nf], 0, 0, 0);
                    acc[mf][nf] = __builtin_amdgcn_mfma_f32_16x16x32_bf16(ah[mf], bl[nf], acc[mf][nf], 0, 0, 0);
                }
        }
        __syncthreads();
    }
    #pragma unroll
    for (int nf = 0; nf < 4; nf++){
        int col = colBase + wc*64 + nf*16 + lm;
        float bv = bias[col];
        #pragma unroll
        for (int mf = 0; mf < 4; mf++){
            int row = rowBase + wr*64 + mf*16 + lg*4;
            #pragma unroll
            for (int j = 0; j < 4; j++){
                float o = acc[mf][nf][j] + bv;
                if (ACT) o = fmaxf(o, 0.f);
                size_t idx = (size_t)(row + j)*Nout + col;
                if (EPI == 0){
                    ((float*)C0)[idx] = o;
                } else if (EPI == 1){
                    u16 hh = f2bf(o);
                    ((u16*)C0)[idx] = hh;
                    ((u16*)C1)[idx] = f2bf(o - bf2f(hh));
                } else {
                    ((u16*)C0)[idx] = f2bf(o);
                }
            }
        }
    }
}

// ---------------- BatchNorm (split in / split out) ----------------
__global__ __launch_bounds__(256) void bn_stats_kernel(const u16* __restrict__ Ah,
        const u16* __restrict__ Al, float* __restrict__ sums, int n){
    int c = threadIdx.x;
    int r0 = blockIdx.x*128, r1 = min(n, r0+128);
    float s0=0.f, s1=0.f, q0=0.f, q1=0.f;
    for (int r = r0; r < r1; r++){
        float v0 = bf2f(Ah[(size_t)r*D + c])       + bf2f(Al[(size_t)r*D + c]);
        float v1 = bf2f(Ah[(size_t)r*D + 256 + c]) + bf2f(Al[(size_t)r*D + 256 + c]);
        s0 += v0; q0 += v0*v0; s1 += v1; q1 += v1*v1;
    }
    atomicAdd(&sums[c], s0);
    atomicAdd(&sums[c+256], s1);
    atomicAdd(&sums[512+c], q0);
    atomicAdd(&sums[512+c+256], q1);
}

__global__ void bn_final_kernel(const float* __restrict__ sums, const float* __restrict__ gamma,
        const float* __restrict__ beta, float* __restrict__ sc, int n){
    int c = threadIdx.x;
    float mean = sums[c] / (float)n;
    float var = sums[512+c] / (float)n - mean*mean;
    float r = rsqrtf(var + 1e-5f);
    float scale = r * gamma[c];
    sc[c] = scale;
    sc[512+c] = beta[c] - mean*scale;
}

__global__ void bn_apply_kernel(const u16* __restrict__ inh, const u16* __restrict__ inl,
        const float* __restrict__ sc, u16* __restrict__ oh, u16* __restrict__ ol, int total4){
    int i = blockIdx.x*256 + threadIdx.x;
    if (i >= total4) return;
    int c4 = (i*4) & (D-1);
    us4 vh = *(const us4*)(inh + (size_t)i*4);
    us4 vl = *(const us4*)(inl + (size_t)i*4);
    float4 s  = *(const float4*)(sc + c4);
    float4 sh = *(const float4*)(sc + 512 + c4);
    float sa[4] = {s.x, s.y, s.z, s.w};
    float ba[4] = {sh.x, sh.y, sh.z, sh.w};
    us4 h4, l4;
    #pragma unroll
    for (int j = 0; j < 4; j++){
        float v = bf2f(vh[j]) + bf2f(vl[j]);
        float o = v*sa[j] + ba[j];
        u16 hh = f2bf(o);
        h4[j] = hh;
        l4[j] = f2bf(o - bf2f(hh));
    }
    *(us4*)(oh + (size_t)i*4) = h4;
    *(us4*)(ol + (size_t)i*4) = l4;
}

// ---------------- MFMA ragged masked flash attention (round-8-proven) ----------------
#define ATS 72
__global__ __launch_bounds__(256) void attn_mfma_kernel(const u16* __restrict__ qkH,
        const u16* __restrict__ qkL, const u16* __restrict__ vbf,
        const u64* __restrict__ maskbits,
        const int* __restrict__ ptr, u16* __restrict__ oh, u16* __restrict__ ol, int N){
    __shared__ u16 Kh[64][ATS];
    __shared__ u16 Kl[64][ATS];
    __shared__ u16 Vt[64][ATS];
    __shared__ u16 Pl[4][16][ATS];
    int b = blockIdx.z, h = blockIdx.y;
    int base = ptr[b], size = ptr[b+1] - base;
    int q0 = blockIdx.x * 64;
    if (q0 >= size) return;
    int tid = threadIdx.x, w = tid >> 6, l = tid & 63;
    int lg = l >> 4, lm = l & 15;
    short8 qh[2], ql[2];
    {
        int qrow = q0 + w*16 + lm;
        int qr = (qrow < size) ? qrow : 0;
        const u16* qph = qkH + (size_t)(base + qr)*1024 + 512 + h*64;
        const u16* qpl = qkL + (size_t)(base + qr)*1024 + 512 + h*64;
        #pragma unroll
        for (int ks = 0; ks < 2; ks++){
            short8 th = *(const short8*)(qph + ks*32 + lg*8);
            short8 tl = *(const short8*)(qpl + ks*32 + lg*8);
            if (qrow >= size){ th = short8{0,0,0,0,0,0,0,0}; tl = short8{0,0,0,0,0,0,0,0}; }
            qh[ks] = th; ql[ks] = tl;
        }
    }
    f32x4 acco[4] = {};
    float mrow[4], lrow[4];
    #pragma unroll
    for (int j = 0; j < 4; j++){ mrow[j] = -INFINITY; lrow[j] = 0.f; }
    int nt = (size + 63) >> 6;
    for (int t = 0; t < nt; t++){
        int j0 = t*64;
        __syncthreads();
        {
            int jj = tid & 63, db = (tid >> 6)*16;
            int key = j0 + jj;
            bool ok = key < size;
            size_t node = (size_t)(base + (ok ? key : 0));
            const u16* khp = qkH + node*1024 + h*64 + db;
            const u16* klp = qkL + node*1024 + h*64 + db;
            const u16* vp  = vbf + node*512  + h*64 + db;
            ushort8 z = {0,0,0,0,0,0,0,0};
            ushort8 kh0 = ok ? *(const ushort8*)(khp)     : z;
            ushort8 kh1 = ok ? *(const ushort8*)(khp + 8) : z;
            ushort8 kl0 = ok ? *(const ushort8*)(klp)     : z;
            ushort8 kl1 = ok ? *(const ushort8*)(klp + 8) : z;
            ushort8 v0  = ok ? *(const ushort8*)(vp)      : z;
            ushort8 v1  = ok ? *(const ushort8*)(vp + 8)  : z;
            *(ushort8*)&Kh[jj][db]     = kh0;
            *(ushort8*)&Kh[jj][db + 8] = kh1;
            *(ushort8*)&Kl[jj][db]     = kl0;
            *(ushort8*)&Kl[jj][db + 8] = kl1;
            #pragma unroll
            for (int i = 0; i < 8; i++){
                Vt[db + i][jj]     = v0[i];
                Vt[db + 8 + i][jj] = v1[i];
            }
        }
        __syncthreads();
        f32x4 sc[4] = {};
        #pragma unroll
        for (int nf = 0; nf < 4; nf++)
            #pragma unroll
            for (int ks = 0; ks < 2; ks++){
                short8 kh = *(const short8*)&Kh[nf*16 + lm][ks*32 + lg*8];
                short8 kl = *(const short8*)&Kl[nf*16 + lm][ks*32 + lg*8];
                sc[nf] = __builtin_amdgcn_mfma_f32_16x16x32_bf16(qh[ks], kh, sc[nf], 0, 0, 0);
                sc[nf] = __builtin_amdgcn_mfma_f32_16x16x32_bf16(ql[ks], kh, sc[nf], 0, 0, 0);
                sc[nf] = __builtin_amdgcn_mfma_f32_16x16x32_bf16(qh[ks], kl, sc[nf], 0, 0, 0);
            }
        u64 mb[4];
        #pragma unroll
        for (int j = 0; j < 4; j++)
            mb[j] = maskbits[((size_t)b*LMAX + (q0 + w*16 + lg*4 + j))*8 + t];
        float mx[4], alpha[4];
        #pragma unroll
        for (int j = 0; j < 4; j++){
            float s0 = -INFINITY;
            #pragma unroll
            for (int nf = 0; nf < 4; nf++){
                int key = j0 + nf*16 + lm;
                float s = sc[nf][j] * 0.125f;
                bool msk = (key >= size) || ((mb[j] >> (nf*16 + lm)) & 1);
                s = msk ? -INFINITY : s;
                sc[nf][j] = s;
                s0 = fmaxf(s0, s);
            }
            #pragma unroll
            for (int off = 1; off < 16; off <<= 1) s0 = fmaxf(s0, __shfl_xor(s0, off));
            mx[j] = s0;
        }
        #pragma unroll
        for (int j = 0; j < 4; j++){
            if (mx[j] == -INFINITY){ alpha[j] = 1.f; }
            else {
                float mn = fmaxf(mrow[j], mx[j]);
                alpha[j] = __expf(mrow[j] - mn);
                mrow[j] = mn;
            }
        }
        float ps[4] = {0.f, 0.f, 0.f, 0.f};
        #pragma unroll
        for (int nf = 0; nf < 4; nf++)
            #pragma unroll
            for (int j = 0; j < 4; j++){
                float p = (mx[j] == -INFINITY) ? 0.f : __expf(sc[nf][j] - mrow[j]);
                ps[j] += p;
                Pl[w][lg*4 + j][nf*16 + lm] = f2bf(p);
            }
        #pragma unroll
        for (int j = 0; j < 4; j++){
            float s = ps[j];
            #pragma unroll
            for (int off = 1; off < 16; off <<= 1) s += __shfl_xor(s, off);
            lrow[j] = lrow[j]*alpha[j] + s;
        }
        #pragma unroll
        for (int df = 0; df < 4; df++)
            #pragma unroll
            for (int j = 0; j < 4; j++) acco[df][j] *= alpha[j];
        #pragma unroll
        for (int ks = 0; ks < 2; ks++){
            short8 pf = *(const short8*)&Pl[w][lm][ks*32 + lg*8];
            #pragma unroll
            for (int df = 0; df < 4; df++){
                short8 vf = *(const short8*)&Vt[df*16 + lm][ks*32 + lg*8];
                acco[df] = __builtin_amdgcn_mfma_f32_16x16x32_bf16(pf, vf, acco[df], 0, 0, 0);
            }
        }
    }
    #pragma unroll
    for (int j = 0; j < 4; j++){
        int r = q0 + w*16 + lg*4 + j;
        if (r < size){
            float inv = 1.f / lrow[j];
            #pragma unroll
            for (int df = 0; df < 4; df++){
                float o = acco[df][j] * inv;
                size_t idx = (size_t)(base + r)*D + h*64 + df*16 + lm;
                u16 hh = f2bf(o);
                oh[idx] = hh;
                ol[idx] = f2bf(o - bf2f(hh));
            }
        }
    }
}

extern "C" void kernel_launch(void* const* d_in, const int* in_sizes, int n_in,
                              void* d_out, int out_size, void* d_ws, size_t ws_size,
                              hipStream_t stream){
    const float* x        = (const float*)d_in[0];
    const int*   ei_raw   = (const int*)d_in[1];
    const unsigned char* mask_raw = (const unsigned char*)d_in[2];
    const int*   ptr_raw  = (const int*)d_in[3];
    const float* gin_w1   = (const float*)d_in[4];
    const float* gin_b1   = (const float*)d_in[5];
    const float* gin_w2   = (const float*)d_in[6];
    const float* gin_b2   = (const float*)d_in[7];
    const float* bn_gamma = (const float*)d_in[8];
    const float* bn_beta  = (const float*)d_in[9];
    const float* se_w     = (const float*)d_in[10];
    const float* se_b     = (const float*)d_in[11];
    const float* qk_w     = (const float*)d_in[12];
    const float* qk_b     = (const float*)d_in[13];
    const float* v_w      = (const float*)d_in[14];
    const float* v_b      = (const float*)d_in[15];
    const float* out_w    = (const float*)d_in[16];
    const float* out_b    = (const float*)d_in[17];

    const int N  = in_sizes[0] / D;       // 12160
    const int E  = in_sizes[1] / 2;       // 97280
    const int B  = in_sizes[3] - 1;       // 32
    const int Mn = in_sizes[2];           // B*512*512

    char* ws = (char*)d_ws;
    char* p = ws;
    auto alloc = [&](size_t bytes) -> char* {
        char* q = p; p += (bytes + 255) & ~(size_t)255; return q;
    };
    size_t PLANE = (size_t)N * D * sizeof(u16);
    u16* pairX = (u16*)alloc(2*PLANE);
    u16* pairG = (u16*)alloc(2*PLANE);
    u16* pairT = (u16*)alloc(2*PLANE);
    u16* pairH = (u16*)alloc(2*PLANE);
    u16* v_bf  = (u16*)alloc(PLANE);
    u16* Xh = pairX, *Xl = pairX + (size_t)N*D;
    u16* Gh = pairG, *Gl = pairG + (size_t)N*D;
    u16* Th = pairT, *Tl = pairT + (size_t)N*D;
    u16* Hh = pairH, *Hl = pairH + (size_t)N*D;
    float* sums   = (float*)alloc(1024*sizeof(float));
    float* sc     = (float*)alloc(1024*sizeof(float));
    int*   flags  = (int*)alloc(16*sizeof(int));
    int*   deg    = (int*)alloc((size_t)N*sizeof(int));
    int*   offs   = (int*)alloc((size_t)(N+1)*sizeof(int));
    int*   cursor = (int*)alloc((size_t)N*sizeof(int));
    int*   in_src = (int*)alloc((size_t)E*sizeof(int));
    int*   ptr32  = (int*)alloc(64*sizeof(int));
    int*   ei32   = (int*)alloc((size_t)2*E*sizeof(int));
    u64*   mbits  = (u64*)alloc((size_t)(Mn/64)*sizeof(u64));
    u16*   wtsh   = (u16*)alloc((size_t)2883584*sizeof(u16));
    u16*   wtsl   = (u16*)alloc((size_t)2883584*sizeof(u16));
    const size_t SLOT = 262144;
    u16 *wh_v = wtsh, *wl_v = wtsl;
    u16 *wh_g[6], *wl_g[6];
    for (int i = 0; i < 6; i++){ wh_g[i] = wtsh + SLOT*(1+i); wl_g[i] = wtsl + SLOT*(1+i); }
    u16 *wh_se  = wtsh + SLOT*7,  *wl_se  = wtsl + SLOT*7;
    u16 *wh_qk  = wtsh + SLOT*8,  *wl_qk  = wtsl + SLOT*8;
    u16 *wh_out = wtsh + SLOT*10, *wl_out = wtsl + SLOT*10;

    // --- dtype probe + normalization ---
    probe_kernel<<<1, 64, 0, stream>>>(ptr_raw, mask_raw, flags);
    conv_int_kernel<<<1, 64, 0, stream>>>(ptr_raw, ptr32, flags, B + 1);
    conv_int_kernel<<<(2*E + 255)/256, 256, 0, stream>>>(ei_raw, ei32, flags, 2*E);
    maskbits_kernel<<<(Mn/64 + 255)/256, 256, 0, stream>>>(mask_raw, mbits, flags, Mn/64);

    // --- CSR inversion ---
    hipMemsetAsync(deg, 0, (size_t)N*sizeof(int), stream);
    hipMemsetAsync(cursor, 0, (size_t)N*sizeof(int), stream);
    count_kernel<<<(E+255)/256, 256, 0, stream>>>(ei32, deg, E, N);
    scan_kernel<<<1, 1024, 0, stream>>>(deg, offs, N);
    fill_kernel<<<(E+255)/256, 256, 0, stream>>>(ei32, offs, cursor, in_src, E, N);

    // --- weight transpose + split convert ---
    transpose_kernel<<<dim3(16,16), 256, 0, stream>>>(v_w, wh_v, wl_v, D, D);
    for (int i = 0; i < NGIN; i++){
        transpose_kernel<<<dim3(16,16), 256, 0, stream>>>(gin_w1 + (size_t)i*D*D, wh_g[2*i],   wl_g[2*i],   D, D);
        transpose_kernel<<<dim3(16,16), 256, 0, stream>>>(gin_w2 + (size_t)i*D*D, wh_g[2*i+1], wl_g[2*i+1], D, D);
    }
    transpose_kernel<<<dim3(16,16), 256, 0, stream>>>(se_w,  wh_se,  wl_se,  D, D);
    transpose_kernel<<<dim3(32,16), 256, 0, stream>>>(qk_w,  wh_qk,  wl_qk,  D, 2*D);
    transpose_kernel<<<dim3(16,16), 256, 0, stream>>>(out_w, wh_out, wl_out, D, D);

    // x -> split pair X
    split_kernel<<<(N*D/4 + 255)/256, 256, 0, stream>>>(x, Xh, Xl, N*D/4);

    dim3 g512(4, N/128), g1024(8, N/128);

    // v = x @ v_w + v_b  -> plain bf16
    gemm_ps<0,2><<<g512, 256, 0, stream>>>(Xh, Xl, wh_v, wl_v, v_b, v_bf, nullptr, D, D);

    // GIN layers (split activations throughout; layer-0 gather reads split X)
    for (int i = 0; i < NGIN; i++){
        const u16* sh = (i == 0) ? Xh : Hh;
        const u16* sl = (i == 0) ? Xl : Hl;
        gather_kernel<<<(N+1)/2, 256, 0, stream>>>(sh, sl, offs, in_src, Gh, Gl, N);
        gemm_ps<1,1><<<g512, 256, 0, stream>>>(Gh, Gl, wh_g[2*i],   wl_g[2*i],   gin_b1 + (size_t)i*D, Th, Tl, D, D);
        gemm_ps<1,1><<<g512, 256, 0, stream>>>(Th, Tl, wh_g[2*i+1], wl_g[2*i+1], gin_b2 + (size_t)i*D, Hh, Hl, D, D);
    }

    // BatchNorm: pairH -> pairG
    hipMemsetAsync(sums, 0, 1024*sizeof(float), stream);
    bn_stats_kernel<<<(N+127)/128, 256, 0, stream>>>(Hh, Hl, sums, N);
    bn_final_kernel<<<1, 512, 0, stream>>>(sums, bn_gamma, bn_beta, sc, N);
    bn_apply_kernel<<<(N*D/4 + 255)/256, 256, 0, stream>>>(Hh, Hl, sc, Gh, Gl, N*D/4);

    // x_struct = bn @ se_w + se_b : pairG -> pairT (split)
    gemm_ps<0,1><<<g512, 256, 0, stream>>>(Gh, Gl, wh_se, wl_se, se_b, Th, Tl, D, D);

    // qk: pairT -> hi plane = pairX (N x 1024), lo plane = pairG
    gemm_ps<0,1><<<g1024, 256, 0, stream>>>(Th, Tl, wh_qk, wl_qk, qk_b, pairX, pairG, D, 2*D);

    // attention: split qk + bf16 v -> split output in pairT
    attn_mfma_kernel<<<dim3(LMAX/64, NHEAD, B), 256, 0, stream>>>(pairX, pairG, v_bf, mbits, ptr32, Th, Tl, N);

    // out = attn_out @ out_w + out_b -> f32 d_out
    gemm_ps<0,0><<<g512, 256, 0, stream>>>(Th, Tl, wh_out, wl_out, out_b, (float*)d_out, nullptr, D, D);
}

// Round 10
// 592.345 us; speedup vs baseline: 5.2392x; 1.0912x over previous
//
#include <hip/hip_runtime.h>
#include <hip/hip_bf16.h>
#include <cstdint>
#include <cstddef>

#define D 512
#define NHEAD 8
#define LMAX 512
#define NGIN 3

typedef unsigned short u16;
typedef unsigned long long u64;
typedef __attribute__((ext_vector_type(8))) short short8;
typedef __attribute__((ext_vector_type(8))) unsigned short ushort8;
typedef __attribute__((ext_vector_type(4))) unsigned short us4;
typedef __attribute__((ext_vector_type(4))) float f32x4;

static __device__ inline u16 f2bf(float f){            // RNE (for standalone bf16 stores)
    union { float f; uint32_t u; } c; c.f = f;
    uint32_t r = (c.u + 0x7fffu + ((c.u >> 16) & 1u)) >> 16;
    return (u16)r;
}
static __device__ inline u16 tbf(float f){             // truncate (for hi/lo splits: cheap)
    union { float f; uint32_t u; } c; c.f = f;
    return (u16)(c.u >> 16);
}
static __device__ inline float bf2f(u16 h){
    union { uint32_t u; float f; } c; c.u = ((uint32_t)h) << 16; return c.f;
}

#define GLOAD_LDS16(SRC, DST) \
    __builtin_amdgcn_global_load_lds( \
        (const __attribute__((address_space(1))) void*)(SRC), \
        (__attribute__((address_space(3))) void*)(DST), 16, 0, 0)

// ---------------- dtype probe + normalization ----------------
__global__ void probe_kernel(const int* __restrict__ ptr_raw,
                             const unsigned char* __restrict__ mask_raw,
                             int* __restrict__ flags){
    if (threadIdx.x == 0){
        flags[0] = (ptr_raw[1] == 0) ? 1 : 0;
        int cntOdd = 0, cnt4 = 0;
        for (int i = 1; i < 2048; i += 2) cntOdd += (mask_raw[i] != 0);
        for (int i = 4; i < 2048; i += 8) cnt4   += (mask_raw[i] != 0);
        flags[1] = (cntOdd > 64) ? 1 : ((cnt4 > 16) ? 4 : 8);
    }
}

__global__ void conv_int_kernel(const int* __restrict__ raw, int* __restrict__ outp,
                                const int* __restrict__ flags, int n){
    int i = blockIdx.x*256 + threadIdx.x;
    if (i < n) outp[i] = flags[0] ? raw[2*i] : raw[i];
}

__global__ void maskbits_kernel(const unsigned char* __restrict__ raw,
                                u64* __restrict__ outp,
                                const int* __restrict__ flags, int total){
    int idx = blockIdx.x*256 + threadIdx.x;
    if (idx >= total) return;
    int w = flags[1];
    size_t ebase = (size_t)(idx >> 3) * 512 + (size_t)(idx & 7) * 64;
    u64 bits = 0;
    if (w == 1){
        const u64* p8 = (const u64*)(raw + ebase);
        #pragma unroll
        for (int g = 0; g < 8; g++){
            u64 v = p8[g];
            #pragma unroll
            for (int by = 0; by < 8; by++)
                if ((v >> (by*8)) & 0xffull) bits |= 1ull << (g*8 + by);
        }
    } else {
        for (int j = 0; j < 64; j++)
            if (raw[(ebase + j) * (size_t)w]) bits |= 1ull << j;
    }
    outp[idx] = bits;
}

// ---------------- CSR inversion ----------------
__global__ void count_kernel(const int* __restrict__ ei, int* __restrict__ deg, int E, int N){
    int e = blockIdx.x*256 + threadIdx.x;
    if (e < E){
        int d = ei[E + e];
        if ((unsigned)d < (unsigned)N) atomicAdd(&deg[d], 1);
    }
}

__global__ void scan_kernel(const int* __restrict__ deg, int* __restrict__ offs, int n){
    __shared__ int wsum[16];
    __shared__ int carry_s;
    int tid = threadIdx.x, lane = tid & 63, wv = tid >> 6;
    if (tid == 0){ carry_s = 0; offs[0] = 0; }
    __syncthreads();
    int nChunks = (n + 1023) / 1024;
    for (int ch = 0; ch < nChunks; ch++){
        int i = ch*1024 + tid;
        int val = (i < n) ? deg[i] : 0;
        int s = val;
        #pragma unroll
        for (int off = 1; off < 64; off <<= 1){
            int t = __shfl_up(s, off);
            if (lane >= off) s += t;
        }
        if (lane == 63) wsum[wv] = s;
        __syncthreads();
        if (wv == 0){
            int t = (lane < 16) ? wsum[lane] : 0;
            #pragma unroll
            for (int off = 1; off < 16; off <<= 1){
                int u = __shfl_up(t, off);
                if (lane >= off) t += u;
            }
            if (lane < 16) wsum[lane] = t;
        }
        __syncthreads();
        int wbase = wv ? wsum[wv-1] : 0;
        if (i < n) offs[i+1] = carry_s + wbase + s;
        __syncthreads();
        if (tid == 1023) carry_s += wsum[15];
        __syncthreads();
    }
}

__global__ void fill_kernel(const int* __restrict__ ei, const int* __restrict__ offs,
                            int* __restrict__ cursor, int* __restrict__ in_src, int E, int N){
    int e = blockIdx.x*256 + threadIdx.x;
    if (e < E){
        int d = ei[E + e];
        if ((unsigned)d < (unsigned)N){
            int slot = atomicAdd(&cursor[d], 1);
            in_src[offs[d] + slot] = ei[e];
        }
    }
}

// ---------------- split f32 -> hi/lo bf16 planes (trunc split) ----------------
__global__ void split_kernel(const float* __restrict__ in, u16* __restrict__ hi,
                             u16* __restrict__ lo, int total4){
    int i = blockIdx.x*256 + threadIdx.x;
    if (i >= total4) return;
    float4 v = *(const float4*)(in + (size_t)i*4);
    float fv[4] = {v.x, v.y, v.z, v.w};
    us4 h4, l4;
    #pragma unroll
    for (int j = 0; j < 4; j++){
        u16 hh = tbf(fv[j]);
        h4[j] = hh;
        l4[j] = tbf(fv[j] - bf2f(hh));
    }
    *(us4*)(hi + (size_t)i*4) = h4;
    *(us4*)(lo + (size_t)i*4) = l4;
}

// ---------------- gather (split in/out, us4 vectorized, 2 nodes/block) ----------------
__global__ __launch_bounds__(256) void gather_kernel(const u16* __restrict__ hh,
        const u16* __restrict__ hl,
        const int* __restrict__ offs, const int* __restrict__ in_src,
        u16* __restrict__ oh, u16* __restrict__ ol, int N){
    int node = blockIdx.x*2 + (threadIdx.x >> 7);
    if (node >= N) return;
    int t = threadIdx.x & 127;
    size_t rb = (size_t)node*D + t*4;
    us4 vh = *(const us4*)(hh + rb);
    us4 vl = *(const us4*)(hl + rb);
    float a[4];
    #pragma unroll
    for (int j = 0; j < 4; j++) a[j] = bf2f(vh[j]) + bf2f(vl[j]);
    int s = offs[node], e = offs[node+1];
    for (int i = s; i < e; i++){
        size_t sb = (size_t)in_src[i]*D + t*4;
        us4 nh = *(const us4*)(hh + sb);
        us4 nl = *(const us4*)(hl + sb);
        #pragma unroll
        for (int j = 0; j < 4; j++) a[j] += bf2f(nh[j]) + bf2f(nl[j]);
    }
    us4 h4, l4;
    #pragma unroll
    for (int j = 0; j < 4; j++){
        u16 hh2 = tbf(a[j]);
        h4[j] = hh2;
        l4[j] = tbf(a[j] - bf2f(hh2));
    }
    *(us4*)(oh + rb) = h4;
    *(us4*)(ol + rb) = l4;
}

// ---------------- fat weight transpose + split convert (one launch, z selects matrix) ----------------
// z: 0=v,1=g1[0],2=g2[0],3=g1[1],4=g2[1],5=g1[2],6=g2[2],7=se,8=out,9=qk(Nout=1024)
__global__ __launch_bounds__(256) void transpose_all(
        const float* __restrict__ v_w, const float* __restrict__ gin_w1,
        const float* __restrict__ gin_w2, const float* __restrict__ se_w,
        const float* __restrict__ out_w, const float* __restrict__ qk_w,
        u16* __restrict__ wtsh, u16* __restrict__ wtsl){
    const size_t SLOT = 262144;
    int z = blockIdx.z;
    int Nout = (z == 9) ? 1024 : 512;
    if (z < 9 && blockIdx.x >= 16) return;
    const float* W; int slot;
    switch (z){
        case 0: W = v_w; slot = 0; break;
        case 1: W = gin_w1;               slot = 1; break;
        case 2: W = gin_w2;               slot = 2; break;
        case 3: W = gin_w1 + 262144;      slot = 3; break;
        case 4: W = gin_w2 + 262144;      slot = 4; break;
        case 5: W = gin_w1 + 524288;      slot = 5; break;
        case 6: W = gin_w2 + 524288;      slot = 6; break;
        case 7: W = se_w;  slot = 7; break;
        case 8: W = out_w; slot = 10; break;
        default: W = qk_w; slot = 8; break;
    }
    u16* Wh = wtsh + SLOT*slot;
    u16* Wl = wtsl + SLOT*slot;
    __shared__ float T[32][33];
    int nb = blockIdx.x*32, kb = blockIdx.y*32;
    int ln = threadIdx.x & 31, lk = threadIdx.x >> 5;
    #pragma unroll
    for (int i = 0; i < 4; i++)
        T[lk + 8*i][ln] = W[(size_t)(kb + lk + 8*i)*Nout + nb + ln];
    __syncthreads();
    #pragma unroll
    for (int i = 0; i < 4; i++){
        float val = T[ln][lk + 8*i];
        u16 h = tbf(val);
        size_t idx = (size_t)(nb + lk + 8*i)*512 + kb + ln;
        Wh[idx] = h;
        Wl[idx] = tbf(val - bf2f(h));
    }
}

// ---------------- split-bf16 MFMA GEMM, global_load_lds + XOR-swizzle + XCD swizzle ----------------
// EPI: 0 = f32 out, 1 = split out (C0 hi, C1 lo), 2 = plain bf16 out.
template<int ACT, int EPI>
__global__ __launch_bounds__(256) void gemm_ps(const u16* __restrict__ Ahg,
        const u16* __restrict__ Alg,
        const u16* __restrict__ Wth, const u16* __restrict__ Wtl,
        const float* __restrict__ bias,
        void* __restrict__ C0, void* __restrict__ C1, int K, int Nout){
    __shared__ __align__(16) u16 Ah[128][64];
    __shared__ __align__(16) u16 Al[128][64];
    __shared__ __align__(16) u16 Bh[128][64];
    __shared__ __align__(16) u16 Bl[128][64];
    int tid = threadIdx.x;
    // XCD-aware bijective remap (m204): same-row blocks land on one XCD's L2.
    int gx = gridDim.x;
    int nwg = gx * gridDim.y;
    int orig = blockIdx.x + gx*blockIdx.y;
    int q8 = nwg >> 3, r8 = nwg & 7;
    int xcd = orig & 7, pos = orig >> 3;
    int wg = (xcd < r8 ? xcd*(q8+1) : r8*(q8+1) + (xcd - r8)*q8) + pos;
    int rowBase = (wg / gx) * 128, colBase = (wg % gx) * 128;
    int w = tid >> 6, l = tid & 63, lg = l >> 4, lm = l & 15;
    int wr = w >> 1, wc = w & 1;
    f32x4 acc[4][4] = {};
    const u16* Ahp = Ahg + (size_t)rowBase*K;
    const u16* Alp = Alg + (size_t)rowBase*K;
    const u16* Wph = Wth + (size_t)colBase*K;
    const u16* Wpl = Wtl + (size_t)colBase*K;
    int srow[4], scol[4];
    #pragma unroll
    for (int c = 0; c < 4; c++){
        int slot = c*256 + tid;
        srow[c] = slot >> 3;
        scol[c] = ((slot & 7) ^ (srow[c] & 7)) * 8;
    }
    for (int k0 = 0; k0 < K; k0 += 64){
        #pragma unroll
        for (int c = 0; c < 4; c++){
            int slot = c*256 + tid;
            size_t so = (size_t)srow[c]*K + k0 + scol[c];
            GLOAD_LDS16(Ahp + so, &Ah[0][0] + slot*8);
            GLOAD_LDS16(Alp + so, &Al[0][0] + slot*8);
            GLOAD_LDS16(Wph + so, &Bh[0][0] + slot*8);
            GLOAD_LDS16(Wpl + so, &Bl[0][0] + slot*8);
        }
        __syncthreads();
        #pragma unroll
        for (int ks = 0; ks < 2; ks++){
            int scg = ((ks*4 + lg) ^ (lm & 7)) * 8;
            short8 ah[4], al[4], bh[4], bl[4];
            #pragma unroll
            for (int mf = 0; mf < 4; mf++){
                ah[mf] = *(const short8*)&Ah[wr*64 + mf*16 + lm][scg];
                al[mf] = *(const short8*)&Al[wr*64 + mf*16 + lm][scg];
            }
            #pragma unroll
            for (int nf = 0; nf < 4; nf++){
                bh[nf] = *(const short8*)&Bh[wc*64 + nf*16 + lm][scg];
                bl[nf] = *(const short8*)&Bl[wc*64 + nf*16 + lm][scg];
            }
            __builtin_amdgcn_s_setprio(1);
            #pragma unroll
            for (int mf = 0; mf < 4; mf++)
                #pragma unroll
                for (int nf = 0; nf < 4; nf++){
                    acc[mf][nf] = __builtin_amdgcn_mfma_f32_16x16x32_bf16(ah[mf], bh[nf], acc[mf][nf], 0, 0, 0);
                    acc[mf][nf] = __builtin_amdgcn_mfma_f32_16x16x32_bf16(al[mf], bh[nf], acc[mf][nf], 0, 0, 0);
                    acc[mf][nf] = __builtin_amdgcn_mfma_f32_16x16x32_bf16(ah[mf], bl[nf], acc[mf][nf], 0, 0, 0);
                }
            __builtin_amdgcn_s_setprio(0);
        }
        __syncthreads();
    }
    #pragma unroll
    for (int nf = 0; nf < 4; nf++){
        int col = colBase + wc*64 + nf*16 + lm;
        float bv = bias[col];
        #pragma unroll
        for (int mf = 0; mf < 4; mf++){
            int row = rowBase + wr*64 + mf*16 + lg*4;
            #pragma unroll
            for (int j = 0; j < 4; j++){
                float o = acc[mf][nf][j] + bv;
                if (ACT) o = fmaxf(o, 0.f);
                size_t idx = (size_t)(row + j)*Nout + col;
                if (EPI == 0){
                    ((float*)C0)[idx] = o;
                } else if (EPI == 1){
                    u16 hh = tbf(o);
                    ((u16*)C0)[idx] = hh;
                    ((u16*)C1)[idx] = tbf(o - bf2f(hh));
                } else {
                    ((u16*)C0)[idx] = f2bf(o);
                }
            }
        }
    }
}

// ---------------- BatchNorm (split in / split out) ----------------
__global__ __launch_bounds__(256) void bn_stats_kernel(const u16* __restrict__ Ah,
        const u16* __restrict__ Al, float* __restrict__ sums, int n){
    int c = threadIdx.x;
    int r0 = blockIdx.x*128, r1 = min(n, r0+128);
    float s0=0.f, s1=0.f, q0=0.f, q1=0.f;
    for (int r = r0; r < r1; r++){
        float v0 = bf2f(Ah[(size_t)r*D + c])       + bf2f(Al[(size_t)r*D + c]);
        float v1 = bf2f(Ah[(size_t)r*D + 256 + c]) + bf2f(Al[(size_t)r*D + 256 + c]);
        s0 += v0; q0 += v0*v0; s1 += v1; q1 += v1*v1;
    }
    atomicAdd(&sums[c], s0);
    atomicAdd(&sums[c+256], s1);
    atomicAdd(&sums[512+c], q0);
    atomicAdd(&sums[512+c+256], q1);
}

__global__ void bn_final_kernel(const float* __restrict__ sums, const float* __restrict__ gamma,
        const float* __restrict__ beta, float* __restrict__ sc, int n){
    int c = threadIdx.x;
    float mean = sums[c] / (float)n;
    float var = sums[512+c] / (float)n - mean*mean;
    float r = rsqrtf(var + 1e-5f);
    float scale = r * gamma[c];
    sc[c] = scale;
    sc[512+c] = beta[c] - mean*scale;
}

__global__ void bn_apply_kernel(const u16* __restrict__ inh, const u16* __restrict__ inl,
        const float* __restrict__ sc, u16* __restrict__ oh, u16* __restrict__ ol, int total4){
    int i = blockIdx.x*256 + threadIdx.x;
    if (i >= total4) return;
    int c4 = (i*4) & (D-1);
    us4 vh = *(const us4*)(inh + (size_t)i*4);
    us4 vl = *(const us4*)(inl + (size_t)i*4);
    float4 s  = *(const float4*)(sc + c4);
    float4 sh = *(const float4*)(sc + 512 + c4);
    float sa[4] = {s.x, s.y, s.z, s.w};
    float ba[4] = {sh.x, sh.y, sh.z, sh.w};
    us4 h4, l4;
    #pragma unroll
    for (int j = 0; j < 4; j++){
        float v = bf2f(vh[j]) + bf2f(vl[j]);
        float o = v*sa[j] + ba[j];
        u16 hh = tbf(o);
        h4[j] = hh;
        l4[j] = tbf(o - bf2f(hh));
    }
    *(us4*)(oh + (size_t)i*4) = h4;
    *(us4*)(ol + (size_t)i*4) = l4;
}

// ---------------- MFMA ragged masked flash attention ----------------
#define ATS 72
__global__ __launch_bounds__(256) void attn_mfma_kernel(const u16* __restrict__ qkH,
        const u16* __restrict__ qkL, const u16* __restrict__ vbf,
        const u64* __restrict__ maskbits,
        const int* __restrict__ ptr, u16* __restrict__ oh, u16* __restrict__ ol, int N){
    __shared__ u16 Kh[64][ATS];
    __shared__ u16 Kl[64][ATS];
    __shared__ u16 Vt[64][ATS];
    __shared__ u16 Pl[4][16][ATS];
    int b = blockIdx.z, h = blockIdx.y;
    int base = ptr[b], size = ptr[b+1] - base;
    int q0 = blockIdx.x * 64;
    if (q0 >= size) return;
    int tid = threadIdx.x, w = tid >> 6, l = tid & 63;
    int lg = l >> 4, lm = l & 15;
    short8 qh[2], ql[2];
    {
        int qrow = q0 + w*16 + lm;
        int qr = (qrow < size) ? qrow : 0;
        const u16* qph = qkH + (size_t)(base + qr)*1024 + 512 + h*64;
        const u16* qpl = qkL + (size_t)(base + qr)*1024 + 512 + h*64;
        #pragma unroll
        for (int ks = 0; ks < 2; ks++){
            short8 th = *(const short8*)(qph + ks*32 + lg*8);
            short8 tl = *(const short8*)(qpl + ks*32 + lg*8);
            if (qrow >= size){ th = short8{0,0,0,0,0,0,0,0}; tl = short8{0,0,0,0,0,0,0,0}; }
            qh[ks] = th; ql[ks] = tl;
        }
    }
    f32x4 acco[4] = {};
    float mrow[4], lrow[4];
    #pragma unroll
    for (int j = 0; j < 4; j++){ mrow[j] = -INFINITY; lrow[j] = 0.f; }
    int nt = (size + 63) >> 6;
    for (int t = 0; t < nt; t++){
        int j0 = t*64;
        __syncthreads();
        {
            int jj = tid & 63, db = (tid >> 6)*16;
            int key = j0 + jj;
            bool ok = key < size;
            size_t node = (size_t)(base + (ok ? key : 0));
            const u16* khp = qkH + node*1024 + h*64 + db;
            const u16* klp = qkL + node*1024 + h*64 + db;
            const u16* vp  = vbf + node*512  + h*64 + db;
            ushort8 z = {0,0,0,0,0,0,0,0};
            ushort8 kh0 = ok ? *(const ushort8*)(khp)     : z;
            ushort8 kh1 = ok ? *(const ushort8*)(khp + 8) : z;
            ushort8 kl0 = ok ? *(const ushort8*)(klp)     : z;
            ushort8 kl1 = ok ? *(const ushort8*)(klp + 8) : z;
            ushort8 v0  = ok ? *(const ushort8*)(vp)      : z;
            ushort8 v1  = ok ? *(const ushort8*)(vp + 8)  : z;
            *(ushort8*)&Kh[jj][db]     = kh0;
            *(ushort8*)&Kh[jj][db + 8] = kh1;
            *(ushort8*)&Kl[jj][db]     = kl0;
            *(ushort8*)&Kl[jj][db + 8] = kl1;
            #pragma unroll
            for (int i = 0; i < 8; i++){
                Vt[db + i][jj]     = v0[i];
                Vt[db + 8 + i][jj] = v1[i];
            }
        }
        __syncthreads();
        f32x4 sc[4] = {};
        __builtin_amdgcn_s_setprio(1);
        #pragma unroll
        for (int nf = 0; nf < 4; nf++)
            #pragma unroll
            for (int ks = 0; ks < 2; ks++){
                short8 kh = *(const short8*)&Kh[nf*16 + lm][ks*32 + lg*8];
                short8 kl = *(const short8*)&Kl[nf*16 + lm][ks*32 + lg*8];
                sc[nf] = __builtin_amdgcn_mfma_f32_16x16x32_bf16(qh[ks], kh, sc[nf], 0, 0, 0);
                sc[nf] = __builtin_amdgcn_mfma_f32_16x16x32_bf16(ql[ks], kh, sc[nf], 0, 0, 0);
                sc[nf] = __builtin_amdgcn_mfma_f32_16x16x32_bf16(qh[ks], kl, sc[nf], 0, 0, 0);
            }
        __builtin_amdgcn_s_setprio(0);
        u64 mb[4];
        #pragma unroll
        for (int j = 0; j < 4; j++)
            mb[j] = maskbits[((size_t)b*LMAX + (q0 + w*16 + lg*4 + j))*8 + t];
        float mx[4], alpha[4];
        #pragma unroll
        for (int j = 0; j < 4; j++){
            float s0 = -INFINITY;
            #pragma unroll
            for (int nf = 0; nf < 4; nf++){
                int key = j0 + nf*16 + lm;
                float s = sc[nf][j] * 0.125f;
                bool msk = (key >= size) || ((mb[j] >> (nf*16 + lm)) & 1);
                s = msk ? -INFINITY : s;
                sc[nf][j] = s;
                s0 = fmaxf(s0, s);
            }
            #pragma unroll
            for (int off = 1; off < 16; off <<= 1) s0 = fmaxf(s0, __shfl_xor(s0, off));
            mx[j] = s0;
        }
        #pragma unroll
        for (int j = 0; j < 4; j++){
            if (mx[j] == -INFINITY){ alpha[j] = 1.f; }
            else {
                float mn = fmaxf(mrow[j], mx[j]);
                alpha[j] = __expf(mrow[j] - mn);
                mrow[j] = mn;
            }
        }
        float ps[4] = {0.f, 0.f, 0.f, 0.f};
        #pragma unroll
        for (int nf = 0; nf < 4; nf++)
            #pragma unroll
            for (int j = 0; j < 4; j++){
                float p = (mx[j] == -INFINITY) ? 0.f : __expf(sc[nf][j] - mrow[j]);
                ps[j] += p;
                Pl[w][lg*4 + j][nf*16 + lm] = tbf(p);
            }
        #pragma unroll
        for (int j = 0; j < 4; j++){
            float s = ps[j];
            #pragma unroll
            for (int off = 1; off < 16; off <<= 1) s += __shfl_xor(s, off);
            lrow[j] = lrow[j]*alpha[j] + s;
        }
        #pragma unroll
        for (int df = 0; df < 4; df++)
            #pragma unroll
            for (int j = 0; j < 4; j++) acco[df][j] *= alpha[j];
        __builtin_amdgcn_s_setprio(1);
        #pragma unroll
        for (int ks = 0; ks < 2; ks++){
            short8 pf = *(const short8*)&Pl[w][lm][ks*32 + lg*8];
            #pragma unroll
            for (int df = 0; df < 4; df++){
                short8 vf = *(const short8*)&Vt[df*16 + lm][ks*32 + lg*8];
                acco[df] = __builtin_amdgcn_mfma_f32_16x16x32_bf16(pf, vf, acco[df], 0, 0, 0);
            }
        }
        __builtin_amdgcn_s_setprio(0);
    }
    #pragma unroll
    for (int j = 0; j < 4; j++){
        int r = q0 + w*16 + lg*4 + j;
        if (r < size){
            float inv = 1.f / lrow[j];
            #pragma unroll
            for (int df = 0; df < 4; df++){
                float o = acco[df][j] * inv;
                size_t idx = (size_t)(base + r)*D + h*64 + df*16 + lm;
                u16 hh = tbf(o);
                oh[idx] = hh;
                ol[idx] = tbf(o - bf2f(hh));
            }
        }
    }
}

extern "C" void kernel_launch(void* const* d_in, const int* in_sizes, int n_in,
                              void* d_out, int out_size, void* d_ws, size_t ws_size,
                              hipStream_t stream){
    const float* x        = (const float*)d_in[0];
    const int*   ei_raw   = (const int*)d_in[1];
    const unsigned char* mask_raw = (const unsigned char*)d_in[2];
    const int*   ptr_raw  = (const int*)d_in[3];
    const float* gin_w1   = (const float*)d_in[4];
    const float* gin_b1   = (const float*)d_in[5];
    const float* gin_w2   = (const float*)d_in[6];
    const float* gin_b2   = (const float*)d_in[7];
    const float* bn_gamma = (const float*)d_in[8];
    const float* bn_beta  = (const float*)d_in[9];
    const float* se_w     = (const float*)d_in[10];
    const float* se_b     = (const float*)d_in[11];
    const float* qk_w     = (const float*)d_in[12];
    const float* qk_b     = (const float*)d_in[13];
    const float* v_w      = (const float*)d_in[14];
    const float* v_b      = (const float*)d_in[15];
    const float* out_w    = (const float*)d_in[16];
    const float* out_b    = (const float*)d_in[17];

    const int N  = in_sizes[0] / D;       // 12160
    const int E  = in_sizes[1] / 2;       // 97280
    const int B  = in_sizes[3] - 1;       // 32
    const int Mn = in_sizes[2];           // B*512*512

    char* ws = (char*)d_ws;
    char* p = ws;
    auto alloc = [&](size_t bytes) -> char* {
        char* q = p; p += (bytes + 255) & ~(size_t)255; return q;
    };
    size_t PLANE = (size_t)N * D * sizeof(u16);
    u16* pairX = (u16*)alloc(2*PLANE);
    u16* pairG = (u16*)alloc(2*PLANE);
    u16* pairT = (u16*)alloc(2*PLANE);
    u16* pairH = (u16*)alloc(2*PLANE);
    u16* v_bf  = (u16*)alloc(PLANE);
    u16* Xh = pairX, *Xl = pairX + (size_t)N*D;
    u16* Gh = pairG, *Gl = pairG + (size_t)N*D;
    u16* Th = pairT, *Tl = pairT + (size_t)N*D;
    u16* Hh = pairH, *Hl = pairH + (size_t)N*D;
    float* sums   = (float*)alloc(1024*sizeof(float));
    float* sc     = (float*)alloc(1024*sizeof(float));
    int*   flags  = (int*)alloc(16*sizeof(int));
    int*   deg    = (int*)alloc((size_t)N*sizeof(int));
    int*   offs   = (int*)alloc((size_t)(N+1)*sizeof(int));
    int*   cursor = (int*)alloc((size_t)N*sizeof(int));
    int*   in_src = (int*)alloc((size_t)E*sizeof(int));
    int*   ptr32  = (int*)alloc(64*sizeof(int));
    int*   ei32   = (int*)alloc((size_t)2*E*sizeof(int));
    u64*   mbits  = (u64*)alloc((size_t)(Mn/64)*sizeof(u64));
    u16*   wtsh   = (u16*)alloc((size_t)2883584*sizeof(u16));
    u16*   wtsl   = (u16*)alloc((size_t)2883584*sizeof(u16));
    const size_t SLOT = 262144;
    u16 *wh_v = wtsh, *wl_v = wtsl;
    u16 *wh_g[6], *wl_g[6];
    for (int i = 0; i < 6; i++){ wh_g[i] = wtsh + SLOT*(1+i); wl_g[i] = wtsl + SLOT*(1+i); }
    u16 *wh_se  = wtsh + SLOT*7,  *wl_se  = wtsl + SLOT*7;
    u16 *wh_qk  = wtsh + SLOT*8,  *wl_qk  = wtsl + SLOT*8;
    u16 *wh_out = wtsh + SLOT*10, *wl_out = wtsl + SLOT*10;

    // --- dtype probe + normalization ---
    probe_kernel<<<1, 64, 0, stream>>>(ptr_raw, mask_raw, flags);
    conv_int_kernel<<<1, 64, 0, stream>>>(ptr_raw, ptr32, flags, B + 1);
    conv_int_kernel<<<(2*E + 255)/256, 256, 0, stream>>>(ei_raw, ei32, flags, 2*E);
    maskbits_kernel<<<(Mn/64 + 255)/256, 256, 0, stream>>>(mask_raw, mbits, flags, Mn/64);

    // --- CSR inversion ---
    hipMemsetAsync(deg, 0, (size_t)N*sizeof(int), stream);
    hipMemsetAsync(cursor, 0, (size_t)N*sizeof(int), stream);
    count_kernel<<<(E+255)/256, 256, 0, stream>>>(ei32, deg, E, N);
    scan_kernel<<<1, 1024, 0, stream>>>(deg, offs, N);
    fill_kernel<<<(E+255)/256, 256, 0, stream>>>(ei32, offs, cursor, in_src, E, N);

    // --- fat transpose (one launch for all 11 weight matrices) ---
    transpose_all<<<dim3(32,16,10), 256, 0, stream>>>(v_w, gin_w1, gin_w2, se_w, out_w, qk_w, wtsh, wtsl);

    // x -> split pair X
    split_kernel<<<(N*D/4 + 255)/256, 256, 0, stream>>>(x, Xh, Xl, N*D/4);

    dim3 g512(4, N/128), g1024(8, N/128);

    // v = x @ v_w + v_b  -> plain bf16
    gemm_ps<0,2><<<g512, 256, 0, stream>>>(Xh, Xl, wh_v, wl_v, v_b, v_bf, nullptr, D, D);

    // GIN layers
    for (int i = 0; i < NGIN; i++){
        const u16* sh = (i == 0) ? Xh : Hh;
        const u16* sl = (i == 0) ? Xl : Hl;
        gather_kernel<<<(N+1)/2, 256, 0, stream>>>(sh, sl, offs, in_src, Gh, Gl, N);
        gemm_ps<1,1><<<g512, 256, 0, stream>>>(Gh, Gl, wh_g[2*i],   wl_g[2*i],   gin_b1 + (size_t)i*D, Th, Tl, D, D);
        gemm_ps<1,1><<<g512, 256, 0, stream>>>(Th, Tl, wh_g[2*i+1], wl_g[2*i+1], gin_b2 + (size_t)i*D, Hh, Hl, D, D);
    }

    // BatchNorm: pairH -> pairG
    hipMemsetAsync(sums, 0, 1024*sizeof(float), stream);
    bn_stats_kernel<<<(N+127)/128, 256, 0, stream>>>(Hh, Hl, sums, N);
    bn_final_kernel<<<1, 512, 0, stream>>>(sums, bn_gamma, bn_beta, sc, N);
    bn_apply_kernel<<<(N*D/4 + 255)/256, 256, 0, stream>>>(Hh, Hl, sc, Gh, Gl, N*D/4);

    // x_struct = bn @ se_w + se_b : pairG -> pairT (split)
    gemm_ps<0,1><<<g512, 256, 0, stream>>>(Gh, Gl, wh_se, wl_se, se_b, Th, Tl, D, D);

    // qk: pairT -> hi plane = pairX (N x 1024), lo plane = pairG
    gemm_ps<0,1><<<g1024, 256, 0, stream>>>(Th, Tl, wh_qk, wl_qk, qk_b, pairX, pairG, D, 2*D);

    // attention: split qk + bf16 v -> split output in pairT
    attn_mfma_kernel<<<dim3(LMAX/64, NHEAD, B), 256, 0, stream>>>(pairX, pairG, v_bf, mbits, ptr32, Th, Tl, N);

    // out = attn_out @ out_w + out_b -> f32 d_out
    gemm_ps<0,0><<<g512, 256, 0, stream>>>(Th, Tl, wh_out, wl_out, out_b, (float*)d_out, nullptr, D, D);
}